// Round 1
// baseline (3124.580 us; speedup 1.0000x reference)
//
#include <hip/hip_runtime.h>
#include <math.h>

// Problem constants
#define B_ 2
#define S_ 2048
#define D_ 1024
#define H_ 16
#define HD_ 64
#define BHS (B_*H_*S_)          // 65536 rows of [HD]
#define NROWS (B_*S_)           // 4096 token rows

// ---------------------------------------------------------------------------
// Kernel 1: qkv = tokens @ qkv_w.T + qkv_b, stored permuted into q/k/v buffers
// laid out [B, H, S, HD]. 64x64 output tile per block, BK=16, 256 threads,
// each thread computes a 4x4 micro-tile. A 64-column tile always lies within
// one (c, h) pair since 64 | j0.
// ---------------------------------------------------------------------------
__global__ __launch_bounds__(256) void qkv_gemm(
    const float* __restrict__ A,      // [4096, 1024] tokens
    const float* __restrict__ W,      // [3072, 1024] qkv_w
    const float* __restrict__ bias,   // [3072]
    float* __restrict__ qb, float* __restrict__ kb, float* __restrict__ vb) {
  __shared__ float As[16 * 68];
  __shared__ float Bs[16 * 68];
  const int t = threadIdx.x;
  const int n0 = blockIdx.y * 64;
  const int j0 = blockIdx.x * 64;
  const int arow = t >> 2;          // 0..63
  const int kq = (t & 3) * 4;       // 0,4,8,12
  const int ty = t >> 4;            // 0..15
  const int tx = t & 15;            // 0..15

  float acc[4][4] = {};

  for (int k0 = 0; k0 < 1024; k0 += 16) {
    const float4 av = *(const float4*)&A[(n0 + arow) * 1024 + k0 + kq];
    const float4 bv = *(const float4*)&W[(j0 + arow) * 1024 + k0 + kq];
    __syncthreads();
    As[(kq + 0) * 68 + arow] = av.x;
    As[(kq + 1) * 68 + arow] = av.y;
    As[(kq + 2) * 68 + arow] = av.z;
    As[(kq + 3) * 68 + arow] = av.w;
    Bs[(kq + 0) * 68 + arow] = bv.x;
    Bs[(kq + 1) * 68 + arow] = bv.y;
    Bs[(kq + 2) * 68 + arow] = bv.z;
    Bs[(kq + 3) * 68 + arow] = bv.w;
    __syncthreads();
#pragma unroll
    for (int kk = 0; kk < 16; kk++) {
      const float4 a = *(const float4*)&As[kk * 68 + ty * 4];
      const float4 b = *(const float4*)&Bs[kk * 68 + tx * 4];
      const float ar[4] = {a.x, a.y, a.z, a.w};
      const float br[4] = {b.x, b.y, b.z, b.w};
#pragma unroll
      for (int i = 0; i < 4; i++)
#pragma unroll
        for (int j = 0; j < 4; j++) acc[i][j] = fmaf(ar[i], br[j], acc[i][j]);
    }
  }

  // Epilogue: permuted store. j0 is a multiple of 64 so (c,h) constant.
  const int c = j0 >> 10;
  const int h = (j0 >> 6) & 15;
  float* dst = (c == 0) ? qb : (c == 1) ? kb : vb;
#pragma unroll
  for (int i = 0; i < 4; i++) {
    const int n = n0 + ty * 4 + i;
    const int bidx = n >> 11;
    const int s = n & 2047;
    const long base = ((long)(bidx * H_ + h) * S_ + s) * HD_;
#pragma unroll
    for (int j = 0; j < 4; j++) {
      const int col = tx * 4 + j;
      dst[base + col] = acc[i][j] + bias[j0 + col];
    }
  }
}

// ---------------------------------------------------------------------------
// Kernel 2: RoPE + L2 normalize, in place on q and k buffers ([B,H,S,HD]).
// One wave per 64-element row. Pairing via shfl_xor(1), norm via shfl reduce.
// ---------------------------------------------------------------------------
__global__ __launch_bounds__(256) void rope_norm(float* __restrict__ qb,
                                                 float* __restrict__ kb) {
  const int r = blockIdx.x * 4 + (threadIdx.x >> 6);   // 0 .. 2*BHS-1
  const int lane = threadIdx.x & 63;
  float* buf = (r < BHS) ? qb : kb;
  const int row = r & (BHS - 1);
  const int s = row & (S_ - 1);
  const float x = buf[row * 64 + lane];
  const int f = lane >> 1;
  // inv_freq = 10000^(-f/32) = 2^(-f * log2(10000)/32)
  const float theta = (float)s * exp2f(-(float)f * 0.41524101186092034f);
  float sn, cs;
  sincosf(theta, &sn, &cs);
  const float partner = __shfl_xor(x, 1, 64);
  const float rot = fmaf(partner, (lane & 1) ? sn : -sn, x * cs);
  float ss = rot * rot;
#pragma unroll
  for (int off = 32; off; off >>= 1) ss += __shfl_xor(ss, off, 64);
  const float scale = 1.0f / fmaxf(sqrtf(ss), 1e-12f);
  buf[row * 64 + lane] = rot * scale;
}

// ---------------------------------------------------------------------------
// Kernel 3: streaming attention. Scores are bounded in [-1/8, 1/8] (unit q,k)
// so softmax needs no max subtraction: o = sum(exp(s) v) / sum(exp(s)).
// One wave per q row, 4 rows per block; K/V staged in LDS tiles of 64 rows,
// row stride 68 floats (4*17) -> conflict-free float4 and scalar reads.
// Phase A: lane l computes the dot for key (kt+l).
// Phase C: lane l owns output component c=l; weights broadcast via shfl.
// ---------------------------------------------------------------------------
__global__ __launch_bounds__(256) void attn(
    const float* __restrict__ qb, const float* __restrict__ kb,
    const float* __restrict__ vb, float* __restrict__ ob) {
  __shared__ float Ks[64 * 68];
  __shared__ float Vs[64 * 68];
  __shared__ float qs[4][64];
  const int t = threadIdx.x;
  const int w = t >> 6;
  const int lane = t & 63;
  const int bh = blockIdx.x >> 9;           // / (S/4)
  const int qrow = (blockIdx.x & 511) * 4 + w;
  qs[w][lane] = qb[(bh * S_ + qrow) * 64 + lane];
  const int lrow = t >> 4;                  // 0..15
  const int lcol = (t & 15) * 4;            // 0..60

  float accO = 0.0f, dsum = 0.0f;

  for (int kt = 0; kt < S_; kt += 64) {
    __syncthreads();
#pragma unroll
    for (int i = 0; i < 4; i++) {
      const int row = i * 16 + lrow;
      const long g = ((long)bh * S_ + kt + row) * 64 + lcol;
      *(float4*)&Ks[row * 68 + lcol] = *(const float4*)&kb[g];
      *(float4*)&Vs[row * 68 + lcol] = *(const float4*)&vb[g];
    }
    __syncthreads();
    float dot = 0.0f;
#pragma unroll
    for (int c4 = 0; c4 < 64; c4 += 4) {
      const float4 qv = *(const float4*)&qs[w][c4];
      const float4 kv = *(const float4*)&Ks[lane * 68 + c4];
      dot += qv.x * kv.x + qv.y * kv.y + qv.z * kv.z + qv.w * kv.w;
    }
    const float wexp = __expf(dot * 0.125f);   // SCALE = HD^-0.5 = 1/8
    dsum += wexp;
#pragma unroll
    for (int kk = 0; kk < 64; kk++) {
      const float wk = __shfl(wexp, kk, 64);
      accO = fmaf(wk, Vs[kk * 68 + lane], accO);
    }
  }
#pragma unroll
  for (int off = 32; off; off >>= 1) dsum += __shfl_xor(dsum, off, 64);
  ob[(bh * S_ + qrow) * 64 + lane] = accO / dsum;
}

// ---------------------------------------------------------------------------
// Kernel 4: out = O @ out_w.T + out_b. O is [B,H,S,HD]; A-tile loads remap
// k-index d -> (h, hd). A 16-wide k chunk never crosses a head boundary.
// ---------------------------------------------------------------------------
__global__ __launch_bounds__(256) void out_gemm(
    const float* __restrict__ O,      // [B,H,S,HD]
    const float* __restrict__ W,      // [1024, 1024] out_w
    const float* __restrict__ bias,   // [1024]
    float* __restrict__ out) {        // [4096, 1024]
  __shared__ float As[16 * 68];
  __shared__ float Bs[16 * 68];
  const int t = threadIdx.x;
  const int n0 = blockIdx.y * 64;
  const int j0 = blockIdx.x * 64;
  const int arow = t >> 2;
  const int kq = (t & 3) * 4;
  const int ty = t >> 4;
  const int tx = t & 15;

  const int n = n0 + arow;
  const int bidx = n >> 11;
  const int s = n & 2047;

  float acc[4][4] = {};

  for (int k0 = 0; k0 < 1024; k0 += 16) {
    const int h = k0 >> 6;
    const int hd = (k0 & 63) + kq;
    const float4 av =
        *(const float4*)&O[((long)(bidx * H_ + h) * S_ + s) * HD_ + hd];
    const float4 bv = *(const float4*)&W[(j0 + arow) * 1024 + k0 + kq];
    __syncthreads();
    As[(kq + 0) * 68 + arow] = av.x;
    As[(kq + 1) * 68 + arow] = av.y;
    As[(kq + 2) * 68 + arow] = av.z;
    As[(kq + 3) * 68 + arow] = av.w;
    Bs[(kq + 0) * 68 + arow] = bv.x;
    Bs[(kq + 1) * 68 + arow] = bv.y;
    Bs[(kq + 2) * 68 + arow] = bv.z;
    Bs[(kq + 3) * 68 + arow] = bv.w;
    __syncthreads();
#pragma unroll
    for (int kk = 0; kk < 16; kk++) {
      const float4 a = *(const float4*)&As[kk * 68 + ty * 4];
      const float4 b = *(const float4*)&Bs[kk * 68 + tx * 4];
      const float ar[4] = {a.x, a.y, a.z, a.w};
      const float br[4] = {b.x, b.y, b.z, b.w};
#pragma unroll
      for (int i = 0; i < 4; i++)
#pragma unroll
        for (int j = 0; j < 4; j++) acc[i][j] = fmaf(ar[i], br[j], acc[i][j]);
    }
  }

#pragma unroll
  for (int i = 0; i < 4; i++) {
    const int nn = n0 + ty * 4 + i;
#pragma unroll
    for (int j = 0; j < 4; j++) {
      const int col = j0 + tx * 4 + j;
      out[(long)nn * 1024 + col] = acc[i][j] + bias[col];
    }
  }
}

// ---------------------------------------------------------------------------
extern "C" void kernel_launch(void* const* d_in, const int* in_sizes, int n_in,
                              void* d_out, int out_size, void* d_ws,
                              size_t ws_size, hipStream_t stream) {
  const float* tokens = (const float*)d_in[0];   // [2,2048,1024]
  const float* qkv_w = (const float*)d_in[1];    // [3072,1024]
  const float* qkv_b = (const float*)d_in[2];    // [3072]
  const float* out_w = (const float*)d_in[3];    // [1024,1024]
  const float* out_b = (const float*)d_in[4];    // [1024]
  float* out = (float*)d_out;                    // [2,2048,1024]

  float* wsf = (float*)d_ws;
  const size_t per = (size_t)BHS * HD_;          // 4,194,304 floats
  float* qbuf = wsf;
  float* kbuf = qbuf + per;
  float* vbuf = kbuf + per;
  float* obuf = vbuf + per;                      // total 67 MB

  // 1) QKV projection (+ permuted store)
  dim3 g1(48, 64);
  hipLaunchKernelGGL(qkv_gemm, g1, dim3(256), 0, stream, tokens, qkv_w, qkv_b,
                     qbuf, kbuf, vbuf);
  // 2) RoPE + normalize q and k
  hipLaunchKernelGGL(rope_norm, dim3(2 * BHS / 4), dim3(256), 0, stream, qbuf,
                     kbuf);
  // 3) Attention
  hipLaunchKernelGGL(attn, dim3(B_ * H_ * (S_ / 4)), dim3(256), 0, stream,
                     qbuf, kbuf, vbuf, obuf);
  // 4) Output projection
  dim3 g4(16, 64);
  hipLaunchKernelGGL(out_gemm, g4, dim3(256), 0, stream, obuf, out_w, out_b,
                     out);
}

// Round 2
// 657.012 us; speedup vs baseline: 4.7557x; 4.7557x over previous
//
#include <hip/hip_runtime.h>
#include <hip/hip_bf16.h>
#include <math.h>

// Problem constants
#define B_ 2
#define S_ 2048
#define D_ 1024
#define H_ 16
#define HD_ 64
#define BHS (B_*H_*S_)          // 65536 rows of [HD]
#define NROWS (B_*S_)           // 4096 token rows

typedef __attribute__((ext_vector_type(8))) short bf16x8;
typedef __attribute__((ext_vector_type(4))) float f32x4;

__device__ __forceinline__ short f2bf(float x) {
  __hip_bfloat16 h = __float2bfloat16(x);
  return *reinterpret_cast<short*>(&h);
}

// ---------------------------------------------------------------------------
// Kernel 1: qkv = tokens @ qkv_w.T + qkv_b, stored permuted into q/k/v fp32
// buffers laid out [B, H, S, HD]. 64x64 tile, BK=16, 256 threads, 4x4 micro.
// ---------------------------------------------------------------------------
__global__ __launch_bounds__(256) void qkv_gemm(
    const float* __restrict__ A,      // [4096, 1024] tokens
    const float* __restrict__ W,      // [3072, 1024] qkv_w
    const float* __restrict__ bias,   // [3072]
    float* __restrict__ qb, float* __restrict__ kb, float* __restrict__ vb) {
  __shared__ float As[16 * 68];
  __shared__ float Bs[16 * 68];
  const int t = threadIdx.x;
  const int n0 = blockIdx.y * 64;
  const int j0 = blockIdx.x * 64;
  const int arow = t >> 2;          // 0..63
  const int kq = (t & 3) * 4;       // 0,4,8,12
  const int ty = t >> 4;            // 0..15
  const int tx = t & 15;            // 0..15

  float acc[4][4] = {};

  for (int k0 = 0; k0 < 1024; k0 += 16) {
    const float4 av = *(const float4*)&A[(n0 + arow) * 1024 + k0 + kq];
    const float4 bv = *(const float4*)&W[(j0 + arow) * 1024 + k0 + kq];
    __syncthreads();
    As[(kq + 0) * 68 + arow] = av.x;
    As[(kq + 1) * 68 + arow] = av.y;
    As[(kq + 2) * 68 + arow] = av.z;
    As[(kq + 3) * 68 + arow] = av.w;
    Bs[(kq + 0) * 68 + arow] = bv.x;
    Bs[(kq + 1) * 68 + arow] = bv.y;
    Bs[(kq + 2) * 68 + arow] = bv.z;
    Bs[(kq + 3) * 68 + arow] = bv.w;
    __syncthreads();
#pragma unroll
    for (int kk = 0; kk < 16; kk++) {
      const float4 a = *(const float4*)&As[kk * 68 + ty * 4];
      const float4 b = *(const float4*)&Bs[kk * 68 + tx * 4];
      const float ar[4] = {a.x, a.y, a.z, a.w};
      const float br[4] = {b.x, b.y, b.z, b.w};
#pragma unroll
      for (int i = 0; i < 4; i++)
#pragma unroll
        for (int j = 0; j < 4; j++) acc[i][j] = fmaf(ar[i], br[j], acc[i][j]);
    }
  }

  const int c = j0 >> 10;
  const int h = (j0 >> 6) & 15;
  float* dst = (c == 0) ? qb : (c == 1) ? kb : vb;
#pragma unroll
  for (int i = 0; i < 4; i++) {
    const int n = n0 + ty * 4 + i;
    const int bidx = n >> 11;
    const int s = n & 2047;
    const long base = ((long)(bidx * H_ + h) * S_ + s) * HD_;
#pragma unroll
    for (int j = 0; j < 4; j++) {
      const int col = tx * 4 + j;
      dst[base + col] = acc[i][j] + bias[j0 + col];
    }
  }
}

// ---------------------------------------------------------------------------
// Kernel 2: RoPE + L2 normalize. Reads fp32 q/k, writes bf16 q/k.
// One wave per 64-element row.
// ---------------------------------------------------------------------------
__global__ __launch_bounds__(256) void rope_norm(
    const float* __restrict__ qf, const float* __restrict__ kf,
    __hip_bfloat16* __restrict__ qbf, __hip_bfloat16* __restrict__ kbf) {
  const int r = blockIdx.x * 4 + (threadIdx.x >> 6);   // 0 .. 2*BHS-1
  const int lane = threadIdx.x & 63;
  const float* src = (r < BHS) ? qf : kf;
  __hip_bfloat16* dst = (r < BHS) ? qbf : kbf;
  const int row = r & (BHS - 1);
  const int s = row & (S_ - 1);
  const float x = src[row * 64 + lane];
  const int f = lane >> 1;
  // inv_freq = 10000^(-f/32) = 2^(-f * log2(10000)/32)
  const float theta = (float)s * exp2f(-(float)f * 0.41524101186092034f);
  float sn, cs;
  sincosf(theta, &sn, &cs);
  const float partner = __shfl_xor(x, 1, 64);
  const float rot = fmaf(partner, (lane & 1) ? sn : -sn, x * cs);
  float ss = rot * rot;
#pragma unroll
  for (int off = 32; off; off >>= 1) ss += __shfl_xor(ss, off, 64);
  const float scale = 1.0f / fmaxf(sqrtf(ss), 1e-12f);
  dst[row * 64 + lane] = __float2bfloat16(rot * scale);
}

// ---------------------------------------------------------------------------
// Kernel 3: transpose V per (b,h): vf fp32 [B,H,S,64] -> vt bf16 [B,H,64,S].
// 64x64 tile through LDS, coalesced on both sides.
// ---------------------------------------------------------------------------
__global__ __launch_bounds__(256) void v_transpose(
    const float* __restrict__ vf, __hip_bfloat16* __restrict__ vt) {
  __shared__ short Ts[64 * 65];
  const int t = threadIdx.x;
  const int bh = blockIdx.y;
  const int kt = blockIdx.x * 64;
  const int r = t >> 2;           // key row within tile 0..63
  const int cseg = (t & 3) * 16;  // dim segment
  const float* src = vf + ((long)bh * S_ + kt + r) * 64 + cseg;
#pragma unroll
  for (int j = 0; j < 16; j += 4) {
    float4 v = *(const float4*)(src + j);
    Ts[r * 65 + cseg + j + 0] = f2bf(v.x);
    Ts[r * 65 + cseg + j + 1] = f2bf(v.y);
    Ts[r * 65 + cseg + j + 2] = f2bf(v.z);
    Ts[r * 65 + cseg + j + 3] = f2bf(v.w);
  }
  __syncthreads();
  const int d = t >> 2;           // dim 0..63
  const int ks = (t & 3) * 16;    // key segment
  short tmp[16];
#pragma unroll
  for (int j = 0; j < 16; j++) tmp[j] = Ts[(ks + j) * 65 + d];
  short* dstp = (short*)vt + ((long)bh * 64 + d) * S_ + kt + ks;
  *(bf16x8*)dstp = *(const bf16x8*)tmp;
  *(bf16x8*)(dstp + 8) = *(const bf16x8*)(tmp + 8);
}

// ---------------------------------------------------------------------------
// Kernel 4: MFMA streaming attention. Scores in [-1/8,1/8] (unit q,k), so
// no max subtraction: o = sum(exp(s) v) / sum(exp(s)).
// Block = 4 waves; wave w owns q rows [q0+16w, q0+16w+16). K/V tiles of 64
// keys staged in LDS (stride 72 bf16: 16B-aligned, ~2-way banks). QK^T and
// PV via mfma_f32_16x16x32_bf16; P round-trips per-wave LDS (C->A layout).
// ---------------------------------------------------------------------------
#define LDK 72
__global__ __launch_bounds__(256) void attn_mfma(
    const __hip_bfloat16* __restrict__ qb,  // [B,H,S,64]
    const __hip_bfloat16* __restrict__ kb,  // [B,H,S,64]
    const __hip_bfloat16* __restrict__ vt,  // [B,H,64,S]
    float* __restrict__ ob) {               // [B,H,S,64]
  __shared__ short Ks[64 * LDK];
  __shared__ short Vs[64 * LDK];
  __shared__ short Ps[4][16 * LDK];
  const int t = threadIdx.x;
  const int w = t >> 6;
  const int lane = t & 63;
  const int col = lane & 15;
  const int quad = lane >> 4;
  const int bh = blockIdx.y;
  const int q0 = blockIdx.x * 64;

  // Q fragments (A-layout): rows q0+16w+col, k-chunk c covers c*32+quad*8+j
  const short* qrow = (const short*)qb + ((long)bh * S_ + q0 + w * 16 + col) * 64;
  bf16x8 qa0 = *(const bf16x8*)(qrow + quad * 8);
  bf16x8 qa1 = *(const bf16x8*)(qrow + 32 + quad * 8);

  f32x4 oacc[4] = {};
  float lsum[4] = {0.f, 0.f, 0.f, 0.f};

  const int srow = t >> 2;          // staging row 0..63
  const int sseg = (t & 3) * 16;    // staging bf16 segment

  const short* kg = (const short*)kb + (long)bh * S_ * 64;
  const short* vg = (const short*)vt + (long)bh * 64 * S_;

  for (int kt = 0; kt < S_; kt += 64) {
    __syncthreads();
    {
      const short* ksrc = kg + (long)(kt + srow) * 64 + sseg;
      *(bf16x8*)&Ks[srow * LDK + sseg]     = *(const bf16x8*)ksrc;
      *(bf16x8*)&Ks[srow * LDK + sseg + 8] = *(const bf16x8*)(ksrc + 8);
      const short* vsrc = vg + (long)srow * S_ + kt + sseg;
      *(bf16x8*)&Vs[srow * LDK + sseg]     = *(const bf16x8*)vsrc;
      *(bf16x8*)&Vs[srow * LDK + sseg + 8] = *(const bf16x8*)(vsrc + 8);
    }
    __syncthreads();

    // S = Q K^T  (16 q-rows x 64 keys per wave)
    f32x4 sc[4] = {};
#pragma unroll
    for (int nt = 0; nt < 4; nt++) {
      bf16x8 b0 = *(const bf16x8*)&Ks[(nt * 16 + col) * LDK + quad * 8];
      bf16x8 b1 = *(const bf16x8*)&Ks[(nt * 16 + col) * LDK + 32 + quad * 8];
      sc[nt] = __builtin_amdgcn_mfma_f32_16x16x32_bf16(qa0, b0, sc[nt], 0, 0, 0);
      sc[nt] = __builtin_amdgcn_mfma_f32_16x16x32_bf16(qa1, b1, sc[nt], 0, 0, 0);
    }

    // exp + row-sum + write P to per-wave LDS in A-friendly layout
#pragma unroll
    for (int nt = 0; nt < 4; nt++) {
#pragma unroll
      for (int r = 0; r < 4; r++) {
        const float e = __expf(sc[nt][r] * 0.125f);   // SCALE = 1/8
        lsum[r] += e;
        Ps[w][(quad * 4 + r) * LDK + nt * 16 + col] = f2bf(e);
      }
    }

    // P A-fragments (same-wave LDS round trip; compiler inserts lgkmcnt wait)
    bf16x8 pa0 = *(const bf16x8*)&Ps[w][col * LDK + quad * 8];
    bf16x8 pa1 = *(const bf16x8*)&Ps[w][col * LDK + 32 + quad * 8];
#pragma unroll
    for (int nt = 0; nt < 4; nt++) {
      bf16x8 v0 = *(const bf16x8*)&Vs[(nt * 16 + col) * LDK + quad * 8];
      bf16x8 v1 = *(const bf16x8*)&Vs[(nt * 16 + col) * LDK + 32 + quad * 8];
      oacc[nt] = __builtin_amdgcn_mfma_f32_16x16x32_bf16(pa0, v0, oacc[nt], 0, 0, 0);
      oacc[nt] = __builtin_amdgcn_mfma_f32_16x16x32_bf16(pa1, v1, oacc[nt], 0, 0, 0);
    }
  }

  // reduce lsum across the 16 lanes of each quad group (cols of same rows)
#pragma unroll
  for (int r = 0; r < 4; r++) {
    float s = lsum[r];
    s += __shfl_xor(s, 1, 64);
    s += __shfl_xor(s, 2, 64);
    s += __shfl_xor(s, 4, 64);
    s += __shfl_xor(s, 8, 64);
    lsum[r] = s;
  }

  float* orow = ob + ((long)bh * S_ + q0 + w * 16 + quad * 4) * 64;
#pragma unroll
  for (int r = 0; r < 4; r++) {
    const float inv = 1.0f / lsum[r];
#pragma unroll
    for (int nt = 0; nt < 4; nt++) {
      orow[(long)r * 64 + nt * 16 + col] = oacc[nt][r] * inv;
    }
  }
}

// ---------------------------------------------------------------------------
// Kernel 5: out = O @ out_w.T + out_b. O is [B,H,S,HD] fp32.
// ---------------------------------------------------------------------------
__global__ __launch_bounds__(256) void out_gemm(
    const float* __restrict__ O,      // [B,H,S,HD]
    const float* __restrict__ W,      // [1024, 1024] out_w
    const float* __restrict__ bias,   // [1024]
    float* __restrict__ out) {        // [4096, 1024]
  __shared__ float As[16 * 68];
  __shared__ float Bs[16 * 68];
  const int t = threadIdx.x;
  const int n0 = blockIdx.y * 64;
  const int j0 = blockIdx.x * 64;
  const int arow = t >> 2;
  const int kq = (t & 3) * 4;
  const int ty = t >> 4;
  const int tx = t & 15;

  const int n = n0 + arow;
  const int bidx = n >> 11;
  const int s = n & 2047;

  float acc[4][4] = {};

  for (int k0 = 0; k0 < 1024; k0 += 16) {
    const int h = k0 >> 6;
    const int hd = (k0 & 63) + kq;
    const float4 av =
        *(const float4*)&O[((long)(bidx * H_ + h) * S_ + s) * HD_ + hd];
    const float4 bv = *(const float4*)&W[(j0 + arow) * 1024 + k0 + kq];
    __syncthreads();
    As[(kq + 0) * 68 + arow] = av.x;
    As[(kq + 1) * 68 + arow] = av.y;
    As[(kq + 2) * 68 + arow] = av.z;
    As[(kq + 3) * 68 + arow] = av.w;
    Bs[(kq + 0) * 68 + arow] = bv.x;
    Bs[(kq + 1) * 68 + arow] = bv.y;
    Bs[(kq + 2) * 68 + arow] = bv.z;
    Bs[(kq + 3) * 68 + arow] = bv.w;
    __syncthreads();
#pragma unroll
    for (int kk = 0; kk < 16; kk++) {
      const float4 a = *(const float4*)&As[kk * 68 + ty * 4];
      const float4 b = *(const float4*)&Bs[kk * 68 + tx * 4];
      const float ar[4] = {a.x, a.y, a.z, a.w};
      const float br[4] = {b.x, b.y, b.z, b.w};
#pragma unroll
      for (int i = 0; i < 4; i++)
#pragma unroll
        for (int j = 0; j < 4; j++) acc[i][j] = fmaf(ar[i], br[j], acc[i][j]);
    }
  }

#pragma unroll
  for (int i = 0; i < 4; i++) {
    const int nn = n0 + ty * 4 + i;
#pragma unroll
    for (int j = 0; j < 4; j++) {
      const int col = j0 + tx * 4 + j;
      out[(long)nn * 1024 + col] = acc[i][j] + bias[col];
    }
  }
}

// ---------------------------------------------------------------------------
extern "C" void kernel_launch(void* const* d_in, const int* in_sizes, int n_in,
                              void* d_out, int out_size, void* d_ws,
                              size_t ws_size, hipStream_t stream) {
  const float* tokens = (const float*)d_in[0];
  const float* qkv_w = (const float*)d_in[1];
  const float* qkv_b = (const float*)d_in[2];
  const float* out_w = (const float*)d_in[3];
  const float* out_b = (const float*)d_in[4];
  float* out = (float*)d_out;

  float* wsf = (float*)d_ws;
  const size_t per = (size_t)BHS * HD_;          // 4,194,304 elements
  // fp32 buffers
  float* qf = wsf;                               // [0, per)
  float* kf = wsf + per;                         // [per, 2per)
  float* vf = wsf + 2 * per;                     // [2per, 3per)
  float* O  = wsf + 2 * per;                     // alias vf (vf consumed by transpose)
  // bf16 buffers
  __hip_bfloat16* qbf = (__hip_bfloat16*)(wsf + 3 * per);        // 8 MB
  __hip_bfloat16* kbf = (__hip_bfloat16*)(wsf + 3 * per) + per;  // 8 MB
  __hip_bfloat16* vt  = (__hip_bfloat16*)(wsf + per);            // alias kf (kf consumed by rope)
  // total footprint: 4*per floats = 64 MiB

  dim3 g1(48, 64);
  hipLaunchKernelGGL(qkv_gemm, g1, dim3(256), 0, stream, tokens, qkv_w, qkv_b,
                     qf, kf, vf);
  hipLaunchKernelGGL(rope_norm, dim3(2 * BHS / 4), dim3(256), 0, stream, qf,
                     kf, qbf, kbf);
  hipLaunchKernelGGL(v_transpose, dim3(S_ / 64, B_ * H_), dim3(256), 0, stream,
                     vf, vt);
  hipLaunchKernelGGL(attn_mfma, dim3(S_ / 64, B_ * H_), dim3(256), 0, stream,
                     qbf, kbf, vt, O);
  dim3 g4(16, 64);
  hipLaunchKernelGGL(out_gemm, g4, dim3(256), 0, stream, O, out_w, out_b, out);
}

// Round 3
// 260.036 us; speedup vs baseline: 12.0160x; 2.5266x over previous
//
#include <hip/hip_runtime.h>
#include <hip/hip_bf16.h>
#include <math.h>

// Problem constants
#define B_ 2
#define S_ 2048
#define D_ 1024
#define H_ 16
#define HD_ 64
#define BHS (B_*H_*S_)          // 65536 rows of [HD]
#define NROWS (B_*S_)           // 4096 token rows

typedef __attribute__((ext_vector_type(8))) short bf16x8;
typedef __attribute__((ext_vector_type(4))) float f32x4;

__device__ __forceinline__ short f2bf(float x) {
  __hip_bfloat16 h = __float2bfloat16(x);
  return *reinterpret_cast<short*>(&h);
}
__device__ __forceinline__ float bf2f(short x) {
  __hip_bfloat16 h = *reinterpret_cast<__hip_bfloat16*>(&x);
  return __bfloat162float(h);
}

// async 16B global -> LDS (wave-uniform LDS base + lane*16)
__device__ __forceinline__ void gload_lds16(const short* g, short* l) {
  __builtin_amdgcn_global_load_lds(
      (const __attribute__((address_space(1))) void*)g,
      (__attribute__((address_space(3))) void*)l, 16, 0, 0);
}

// ---------------------------------------------------------------------------
// cast fp32 -> bf16, 8 elements per thread
// ---------------------------------------------------------------------------
__global__ __launch_bounds__(256) void cast_bf16(const float* __restrict__ src,
                                                 short* __restrict__ dst,
                                                 int n8) {
  const int i = blockIdx.x * 256 + threadIdx.x;
  if (i >= n8) return;
  const float4 a = *(const float4*)(src + i * 8);
  const float4 b = *(const float4*)(src + i * 8 + 4);
  short tmp[8] = {f2bf(a.x), f2bf(a.y), f2bf(a.z), f2bf(a.w),
                  f2bf(b.x), f2bf(b.y), f2bf(b.z), f2bf(b.w)};
  *(bf16x8*)(dst + i * 8) = *(const bf16x8*)tmp;
}

// ---------------------------------------------------------------------------
// m97-style bf16 MFMA GEMM: C[m,j] = sum_k A[m,k] W[j,k] (+bias), 128x128
// tile, BK=32, 256 threads = 4 waves (2x2), global_load_lds width-16 staging
// with XOR seg-swizzle (store seg = slot_seg ^ (row&3)), ds_read_b128 frags.
//
// Variant 1: qkv projection. A = tokens bf16 [4096,1024], W = qkv_w bf16
// [3072,1024]. Epilogue stores bf16 permuted into q/k/v [B,H,S,64].
// ---------------------------------------------------------------------------
__global__ __launch_bounds__(256) void qkv_mfma(
    const short* __restrict__ A, const short* __restrict__ W,
    const float* __restrict__ bias,
    short* __restrict__ qb, short* __restrict__ kb, short* __restrict__ vb) {
  __shared__ short As[128 * 32];
  __shared__ short Bs[128 * 32];
  const int t = threadIdx.x;
  const int w = t >> 6;
  const int lane = t & 63;
  const int col = lane & 15;
  const int quad = lane >> 4;
  const int wm = w >> 1;
  const int wn = w & 1;
  const int m0 = blockIdx.y * 128;
  const int n0 = blockIdx.x * 128;

  f32x4 acc[4][4] = {};

  for (int k0 = 0; k0 < 1024; k0 += 32) {
    __syncthreads();
#pragma unroll
    for (int i = 0; i < 2; i++) {
      const int c = w * 2 + i;
      const int sl = c * 64 + lane;
      const int row = sl >> 2;
      const int gseg = (sl & 3) ^ (row & 3);
      gload_lds16(&A[(m0 + row) * 1024 + k0 + gseg * 8], As + c * 512);
      gload_lds16(&W[(n0 + row) * 1024 + k0 + gseg * 8], Bs + c * 512);
    }
    __syncthreads();

    bf16x8 af[4], bf[4];
#pragma unroll
    for (int mt = 0; mt < 4; mt++) {
      const int m = wm * 64 + mt * 16 + col;
      af[mt] = *(const bf16x8*)&As[m * 32 + ((quad ^ (m & 3)) * 8)];
    }
#pragma unroll
    for (int nt = 0; nt < 4; nt++) {
      const int n = wn * 64 + nt * 16 + col;
      bf[nt] = *(const bf16x8*)&Bs[n * 32 + ((quad ^ (n & 3)) * 8)];
    }
#pragma unroll
    for (int mt = 0; mt < 4; mt++)
#pragma unroll
      for (int nt = 0; nt < 4; nt++)
        acc[mt][nt] = __builtin_amdgcn_mfma_f32_16x16x32_bf16(
            af[mt], bf[nt], acc[mt][nt], 0, 0, 0);
  }

  // epilogue: j block [j_base, j_base+64) lies in one head (64-aligned)
  const int j_base = n0 + wn * 64;
  const int c = j_base >> 10;
  const int h = (j_base >> 6) & 15;
  short* dst = (c == 0) ? qb : (c == 1) ? kb : vb;
  float bi[4];
#pragma unroll
  for (int nt = 0; nt < 4; nt++) bi[nt] = bias[j_base + nt * 16 + col];
#pragma unroll
  for (int mt = 0; mt < 4; mt++) {
#pragma unroll
    for (int r = 0; r < 4; r++) {
      const int n = m0 + wm * 64 + mt * 16 + quad * 4 + r;
      const int bidx = n >> 11;
      const int s = n & 2047;
      const long base = ((long)(bidx * 16 + h) * 2048 + s) * 64;
#pragma unroll
      for (int nt = 0; nt < 4; nt++)
        dst[base + nt * 16 + col] = f2bf(acc[mt][nt][r] + bi[nt]);
    }
  }
}

// ---------------------------------------------------------------------------
// Variant 2: out projection. A = O bf16 [B,H,S,64] (k -> (h,hd) remap in
// staging), W = out_w bf16 [1024,1024]. Epilogue stores fp32 out + bias.
// ---------------------------------------------------------------------------
__global__ __launch_bounds__(256) void out_mfma(
    const short* __restrict__ O, const short* __restrict__ W,
    const float* __restrict__ bias, float* __restrict__ out) {
  __shared__ short As[128 * 32];
  __shared__ short Bs[128 * 32];
  const int t = threadIdx.x;
  const int w = t >> 6;
  const int lane = t & 63;
  const int col = lane & 15;
  const int quad = lane >> 4;
  const int wm = w >> 1;
  const int wn = w & 1;
  const int m0 = blockIdx.y * 128;
  const int n0 = blockIdx.x * 128;

  f32x4 acc[4][4] = {};

  for (int k0 = 0; k0 < 1024; k0 += 32) {
    __syncthreads();
#pragma unroll
    for (int i = 0; i < 2; i++) {
      const int c = w * 2 + i;
      const int sl = c * 64 + lane;
      const int row = sl >> 2;
      const int gseg = (sl & 3) ^ (row & 3);
      const int n = m0 + row;
      const int bidx = n >> 11;
      const int s = n & 2047;
      const int kk = k0 + gseg * 8;
      const int h = kk >> 6;
      const int hd = kk & 63;
      gload_lds16(&O[((long)(bidx * 16 + h) * 2048 + s) * 64 + hd],
                  As + c * 512);
      gload_lds16(&W[(n0 + row) * 1024 + k0 + gseg * 8], Bs + c * 512);
    }
    __syncthreads();

    bf16x8 af[4], bf[4];
#pragma unroll
    for (int mt = 0; mt < 4; mt++) {
      const int m = wm * 64 + mt * 16 + col;
      af[mt] = *(const bf16x8*)&As[m * 32 + ((quad ^ (m & 3)) * 8)];
    }
#pragma unroll
    for (int nt = 0; nt < 4; nt++) {
      const int n = wn * 64 + nt * 16 + col;
      bf[nt] = *(const bf16x8*)&Bs[n * 32 + ((quad ^ (n & 3)) * 8)];
    }
#pragma unroll
    for (int mt = 0; mt < 4; mt++)
#pragma unroll
      for (int nt = 0; nt < 4; nt++)
        acc[mt][nt] = __builtin_amdgcn_mfma_f32_16x16x32_bf16(
            af[mt], bf[nt], acc[mt][nt], 0, 0, 0);
  }

  float bi[4];
#pragma unroll
  for (int nt = 0; nt < 4; nt++) bi[nt] = bias[n0 + wn * 64 + nt * 16 + col];
#pragma unroll
  for (int mt = 0; mt < 4; mt++) {
#pragma unroll
    for (int r = 0; r < 4; r++) {
      const int n = m0 + wm * 64 + mt * 16 + quad * 4 + r;
#pragma unroll
      for (int nt = 0; nt < 4; nt++)
        out[(long)n * 1024 + n0 + wn * 64 + nt * 16 + col] =
            acc[mt][nt][r] + bi[nt];
    }
  }
}

// ---------------------------------------------------------------------------
// RoPE + L2 normalize, in place on bf16 q/k buffers ([B,H,S,HD]).
// One wave per 64-element row.
// ---------------------------------------------------------------------------
__global__ __launch_bounds__(256) void rope_norm(short* __restrict__ qb,
                                                 short* __restrict__ kb) {
  const int r = blockIdx.x * 4 + (threadIdx.x >> 6);   // 0 .. 2*BHS-1
  const int lane = threadIdx.x & 63;
  short* buf = (r < BHS) ? qb : kb;
  const int row = r & (BHS - 1);
  const int s = row & (S_ - 1);
  const float x = bf2f(buf[row * 64 + lane]);
  const int f = lane >> 1;
  const float theta = (float)s * exp2f(-(float)f * 0.41524101186092034f);
  float sn, cs;
  sincosf(theta, &sn, &cs);
  const float partner = __shfl_xor(x, 1, 64);
  const float rot = fmaf(partner, (lane & 1) ? sn : -sn, x * cs);
  float ss = rot * rot;
#pragma unroll
  for (int off = 32; off; off >>= 1) ss += __shfl_xor(ss, off, 64);
  const float scale = 1.0f / fmaxf(sqrtf(ss), 1e-12f);
  buf[row * 64 + lane] = f2bf(rot * scale);
}

// ---------------------------------------------------------------------------
// transpose V per (b,h): v bf16 [B,H,S,64] -> vt bf16 [B,H,64,S].
// ---------------------------------------------------------------------------
__global__ __launch_bounds__(256) void v_transpose(
    const short* __restrict__ vf, short* __restrict__ vt) {
  __shared__ short Ts[64 * 65];
  const int t = threadIdx.x;
  const int bh = blockIdx.y;
  const int kt = blockIdx.x * 64;
  const int r = t >> 2;           // key row within tile 0..63
  const int cseg = (t & 3) * 16;  // dim segment
  const short* src = vf + ((long)bh * S_ + kt + r) * 64 + cseg;
  *(bf16x8*)&Ts[r * 65 + cseg] = *(const bf16x8*)src;
  *(bf16x8*)&Ts[r * 65 + cseg + 8] = *(const bf16x8*)(src + 8);
  __syncthreads();
  const int d = t >> 2;           // dim 0..63
  const int ks = (t & 3) * 16;    // key segment
  short tmp[16];
#pragma unroll
  for (int j = 0; j < 16; j++) tmp[j] = Ts[(ks + j) * 65 + d];
  short* dstp = vt + ((long)bh * 64 + d) * S_ + kt + ks;
  *(bf16x8*)dstp = *(const bf16x8*)tmp;
  *(bf16x8*)(dstp + 8) = *(const bf16x8*)(tmp + 8);
}

// ---------------------------------------------------------------------------
// MFMA streaming attention (scores in [-1/8,1/8], no max subtraction).
// Block = 4 waves, wave w owns 16 q rows; 64-key K/V LDS tiles (stride 72).
// Output bf16.
// ---------------------------------------------------------------------------
#define LDK 72
__global__ __launch_bounds__(256) void attn_mfma(
    const short* __restrict__ qb,  // [B,H,S,64]
    const short* __restrict__ kb,  // [B,H,S,64]
    const short* __restrict__ vt,  // [B,H,64,S]
    short* __restrict__ ob) {      // [B,H,S,64]
  __shared__ short Ks[64 * LDK];
  __shared__ short Vs[64 * LDK];
  __shared__ short Ps[4][16 * LDK];
  const int t = threadIdx.x;
  const int w = t >> 6;
  const int lane = t & 63;
  const int col = lane & 15;
  const int quad = lane >> 4;
  const int bh = blockIdx.y;
  const int q0 = blockIdx.x * 64;

  const short* qrow = qb + ((long)bh * S_ + q0 + w * 16 + col) * 64;
  bf16x8 qa0 = *(const bf16x8*)(qrow + quad * 8);
  bf16x8 qa1 = *(const bf16x8*)(qrow + 32 + quad * 8);

  f32x4 oacc[4] = {};
  float lsum[4] = {0.f, 0.f, 0.f, 0.f};

  const int srow = t >> 2;
  const int sseg = (t & 3) * 16;

  const short* kg = kb + (long)bh * S_ * 64;
  const short* vg = vt + (long)bh * 64 * S_;

  for (int kt = 0; kt < S_; kt += 64) {
    __syncthreads();
    {
      const short* ksrc = kg + (long)(kt + srow) * 64 + sseg;
      *(bf16x8*)&Ks[srow * LDK + sseg]     = *(const bf16x8*)ksrc;
      *(bf16x8*)&Ks[srow * LDK + sseg + 8] = *(const bf16x8*)(ksrc + 8);
      const short* vsrc = vg + (long)srow * S_ + kt + sseg;
      *(bf16x8*)&Vs[srow * LDK + sseg]     = *(const bf16x8*)vsrc;
      *(bf16x8*)&Vs[srow * LDK + sseg + 8] = *(const bf16x8*)(vsrc + 8);
    }
    __syncthreads();

    f32x4 sc[4] = {};
#pragma unroll
    for (int nt = 0; nt < 4; nt++) {
      bf16x8 b0 = *(const bf16x8*)&Ks[(nt * 16 + col) * LDK + quad * 8];
      bf16x8 b1 = *(const bf16x8*)&Ks[(nt * 16 + col) * LDK + 32 + quad * 8];
      sc[nt] = __builtin_amdgcn_mfma_f32_16x16x32_bf16(qa0, b0, sc[nt], 0, 0, 0);
      sc[nt] = __builtin_amdgcn_mfma_f32_16x16x32_bf16(qa1, b1, sc[nt], 0, 0, 0);
    }

#pragma unroll
    for (int nt = 0; nt < 4; nt++) {
#pragma unroll
      for (int r = 0; r < 4; r++) {
        const float e = __expf(sc[nt][r] * 0.125f);
        lsum[r] += e;
        Ps[w][(quad * 4 + r) * LDK + nt * 16 + col] = f2bf(e);
      }
    }

    bf16x8 pa0 = *(const bf16x8*)&Ps[w][col * LDK + quad * 8];
    bf16x8 pa1 = *(const bf16x8*)&Ps[w][col * LDK + 32 + quad * 8];
#pragma unroll
    for (int nt = 0; nt < 4; nt++) {
      bf16x8 v0 = *(const bf16x8*)&Vs[(nt * 16 + col) * LDK + quad * 8];
      bf16x8 v1 = *(const bf16x8*)&Vs[(nt * 16 + col) * LDK + 32 + quad * 8];
      oacc[nt] = __builtin_amdgcn_mfma_f32_16x16x32_bf16(pa0, v0, oacc[nt], 0, 0, 0);
      oacc[nt] = __builtin_amdgcn_mfma_f32_16x16x32_bf16(pa1, v1, oacc[nt], 0, 0, 0);
    }
  }

#pragma unroll
  for (int r = 0; r < 4; r++) {
    float s = lsum[r];
    s += __shfl_xor(s, 1, 64);
    s += __shfl_xor(s, 2, 64);
    s += __shfl_xor(s, 4, 64);
    s += __shfl_xor(s, 8, 64);
    lsum[r] = s;
  }

  short* orow = ob + ((long)bh * S_ + q0 + w * 16 + quad * 4) * 64;
#pragma unroll
  for (int r = 0; r < 4; r++) {
    const float inv = 1.0f / lsum[r];
#pragma unroll
    for (int nt = 0; nt < 4; nt++)
      orow[(long)r * 64 + nt * 16 + col] = f2bf(oacc[nt][r] * inv);
  }
}

// ---------------------------------------------------------------------------
extern "C" void kernel_launch(void* const* d_in, const int* in_sizes, int n_in,
                              void* d_out, int out_size, void* d_ws,
                              size_t ws_size, hipStream_t stream) {
  const float* tokens = (const float*)d_in[0];
  const float* qkv_w = (const float*)d_in[1];
  const float* qkv_b = (const float*)d_in[2];
  const float* out_w = (const float*)d_in[3];
  const float* out_b = (const float*)d_in[4];
  float* out = (float*)d_out;

  short* ws = (short*)d_ws;
  const size_t per = (size_t)BHS * HD_;      // 4,194,304 elements
  short* tok_bf  = ws;                       // 4M shorts
  short* qkvw_bf = tok_bf + per;             // 3M
  short* outw_bf = qkvw_bf + 3 * per / 4;    // 1M
  short* q_bf    = outw_bf + per / 4;        // 4M
  short* k_bf    = q_bf + per;               // 4M
  short* v_bf    = k_bf + per;               // 4M
  short* vt_bf   = v_bf + per;               // 4M
  short* O_bf    = vt_bf + per;              // 4M  (total 28M shorts = 56 MB)

  // casts
  hipLaunchKernelGGL(cast_bf16, dim3(2048), dim3(256), 0, stream, tokens,
                     tok_bf, (int)(per / 8));
  hipLaunchKernelGGL(cast_bf16, dim3(1536), dim3(256), 0, stream, qkv_w,
                     qkvw_bf, (int)(3 * per / 4 / 8));
  hipLaunchKernelGGL(cast_bf16, dim3(512), dim3(256), 0, stream, out_w,
                     outw_bf, (int)(per / 4 / 8));

  // QKV projection (MFMA) -> bf16 q/k/v in [B,H,S,64]
  hipLaunchKernelGGL(qkv_mfma, dim3(24, 32), dim3(256), 0, stream, tok_bf,
                     qkvw_bf, qkv_b, q_bf, k_bf, v_bf);
  // RoPE + normalize (in place)
  hipLaunchKernelGGL(rope_norm, dim3(2 * BHS / 4), dim3(256), 0, stream, q_bf,
                     k_bf);
  // V transpose
  hipLaunchKernelGGL(v_transpose, dim3(S_ / 64, B_ * H_), dim3(256), 0, stream,
                     v_bf, vt_bf);
  // Attention
  hipLaunchKernelGGL(attn_mfma, dim3(S_ / 64, B_ * H_), dim3(256), 0, stream,
                     q_bf, k_bf, vt_bf, O_bf);
  // Output projection (MFMA)
  hipLaunchKernelGGL(out_mfma, dim3(8, 32), dim3(256), 0, stream, O_bf,
                     outw_bf, out_b, out);
}

// Round 4
// 233.667 us; speedup vs baseline: 13.3719x; 1.1128x over previous
//
#include <hip/hip_runtime.h>
#include <hip/hip_bf16.h>
#include <math.h>

// Problem constants
#define B_ 2
#define S_ 2048
#define D_ 1024
#define H_ 16
#define HD_ 64
#define BHS (B_*H_*S_)          // 65536 rows of [HD]
#define NROWS (B_*S_)           // 4096 token rows

typedef __attribute__((ext_vector_type(8))) short bf16x8;
typedef __attribute__((ext_vector_type(4))) short bf16x4;
typedef __attribute__((ext_vector_type(4))) float f32x4;

__device__ __forceinline__ short f2bf(float x) {
  __hip_bfloat16 h = __float2bfloat16(x);
  return *reinterpret_cast<short*>(&h);
}
__device__ __forceinline__ float bf2f(short x) {
  __hip_bfloat16 h = *reinterpret_cast<__hip_bfloat16*>(&x);
  return __bfloat162float(h);
}

// async 16B global -> LDS (wave-uniform LDS base + lane*16)
__device__ __forceinline__ void gload_lds16(const short* g, short* l) {
  __builtin_amdgcn_global_load_lds(
      (const __attribute__((address_space(1))) void*)g,
      (__attribute__((address_space(3))) void*)l, 16, 0, 0);
}

// ---------------------------------------------------------------------------
// prep: fused fp32->bf16 casts (tokens, qkv_w, out_w) + RoPE sin/cos table.
// 8-elem units: tokens 524288 | qkv_w 393216 | out_w 131072 | table 8192.
// ---------------------------------------------------------------------------
__global__ __launch_bounds__(256) void prep(
    const float* __restrict__ tokens, const float* __restrict__ qkv_w,
    const float* __restrict__ out_w, short* __restrict__ tok_bf,
    short* __restrict__ qkvw_bf, short* __restrict__ outw_bf,
    float* __restrict__ tab) {
  const int i = blockIdx.x * 256 + threadIdx.x;
  const float* src;
  short* dst;
  int j;
  if (i < 524288) {
    src = tokens; dst = tok_bf; j = i;
  } else if (i < 917504) {
    src = qkv_w; dst = qkvw_bf; j = i - 524288;
  } else if (i < 1048576) {
    src = out_w; dst = outw_bf; j = i - 917504;
  } else if (i < 1056768) {
    const int e = (i - 1048576) * 8;     // entry = s*32 + f, f0 aligned to 8
    const int s = e >> 5;
    const int f0 = e & 31;
#pragma unroll
    for (int k = 0; k < 8; k++) {
      const int f = f0 + k;
      const float theta =
          (float)s * exp2f(-(float)f * 0.41524101186092034f);
      float sn, cs;
      sincosf(theta, &sn, &cs);
      tab[(s * 32 + f) * 2] = sn;
      tab[(s * 32 + f) * 2 + 1] = cs;
    }
    return;
  } else {
    return;
  }
  const float4 a = *(const float4*)(src + (long)j * 8);
  const float4 b = *(const float4*)(src + (long)j * 8 + 4);
  short tmp[8] = {f2bf(a.x), f2bf(a.y), f2bf(a.z), f2bf(a.w),
                  f2bf(b.x), f2bf(b.y), f2bf(b.z), f2bf(b.w)};
  *(bf16x8*)(dst + (long)j * 8) = *(const bf16x8*)tmp;
}

// ---------------------------------------------------------------------------
// qkv projection: m97-style bf16 MFMA GEMM, 128x128 tile, BK=32, 4 waves.
// Epilogue: q/k heads stored [B,H,S,64]; v heads transposed per-wave through
// LDS and stored directly as vt [B,H,64,S] (kills the v_transpose kernel).
// ---------------------------------------------------------------------------
__global__ __launch_bounds__(256) void qkv_mfma(
    const short* __restrict__ A, const short* __restrict__ W,
    const float* __restrict__ bias,
    short* __restrict__ qb, short* __restrict__ kb, short* __restrict__ vtb) {
  __shared__ short As[128 * 32];
  __shared__ short Bs[128 * 32];
  __shared__ short Tv[4][64 * 66];
  const int t = threadIdx.x;
  const int w = t >> 6;
  const int lane = t & 63;
  const int col = lane & 15;
  const int quad = lane >> 4;
  const int wm = w >> 1;
  const int wn = w & 1;
  const int m0 = blockIdx.y * 128;
  const int n0 = blockIdx.x * 128;

  f32x4 acc[4][4] = {};

  for (int k0 = 0; k0 < 1024; k0 += 32) {
    __syncthreads();
#pragma unroll
    for (int i = 0; i < 2; i++) {
      const int c = w * 2 + i;
      const int sl = c * 64 + lane;
      const int row = sl >> 2;
      const int gseg = (sl & 3) ^ (row & 3);
      gload_lds16(&A[(m0 + row) * 1024 + k0 + gseg * 8], As + c * 512);
      gload_lds16(&W[(n0 + row) * 1024 + k0 + gseg * 8], Bs + c * 512);
    }
    __syncthreads();

    bf16x8 af[4], bf[4];
#pragma unroll
    for (int mt = 0; mt < 4; mt++) {
      const int m = wm * 64 + mt * 16 + col;
      af[mt] = *(const bf16x8*)&As[m * 32 + ((quad ^ (m & 3)) * 8)];
    }
#pragma unroll
    for (int nt = 0; nt < 4; nt++) {
      const int n = wn * 64 + nt * 16 + col;
      bf[nt] = *(const bf16x8*)&Bs[n * 32 + ((quad ^ (n & 3)) * 8)];
    }
#pragma unroll
    for (int mt = 0; mt < 4; mt++)
#pragma unroll
      for (int nt = 0; nt < 4; nt++)
        acc[mt][nt] = __builtin_amdgcn_mfma_f32_16x16x32_bf16(
            af[mt], bf[nt], acc[mt][nt], 0, 0, 0);
  }

  const int j_base = n0 + wn * 64;    // 64-aligned -> single (c, h)
  const int c = j_base >> 10;
  const int h = (j_base >> 6) & 15;
  float bi[4];
#pragma unroll
  for (int nt = 0; nt < 4; nt++) bi[nt] = bias[j_base + nt * 16 + col];

  if (c < 2) {
    short* dst = (c == 0) ? qb : kb;
#pragma unroll
    for (int mt = 0; mt < 4; mt++) {
#pragma unroll
      for (int r = 0; r < 4; r++) {
        const int n = m0 + wm * 64 + mt * 16 + quad * 4 + r;
        const int bidx = n >> 11;
        const int s = n & 2047;
        const long base = ((long)(bidx * 16 + h) * 2048 + s) * 64;
#pragma unroll
        for (int nt = 0; nt < 4; nt++)
          dst[base + nt * 16 + col] = f2bf(acc[mt][nt][r] + bi[nt]);
      }
    }
  } else {
    // v: per-wave 64x64 (s,d) tile -> LDS -> transposed store to vt[B,H,64,S]
    short* T = &Tv[w][0];
#pragma unroll
    for (int mt = 0; mt < 4; mt++)
#pragma unroll
      for (int r = 0; r < 4; r++)
#pragma unroll
        for (int nt = 0; nt < 4; nt++)
          T[(mt * 16 + quad * 4 + r) * 66 + nt * 16 + col] =
              f2bf(acc[mt][nt][r] + bi[nt]);
    // wave-private: compiler inserts lgkmcnt wait before the reads
    const int bidx = (m0 + wm * 64) >> 11;
    const int s0 = (m0 + wm * 64) & 2047;
#pragma unroll
    for (int pass = 0; pass < 4; pass++) {
      const int d = pass * 16 + (lane >> 2);
      const int ks = (lane & 3) * 16;
      short tmp[16];
#pragma unroll
      for (int j = 0; j < 16; j++) tmp[j] = T[(ks + j) * 66 + d];
      short* dstp = vtb + ((long)(bidx * 16 + h) * 64 + d) * 2048 + s0 + ks;
      *(bf16x8*)dstp = *(const bf16x8*)tmp;
      *(bf16x8*)(dstp + 8) = *(const bf16x8*)(tmp + 8);
    }
  }
}

// ---------------------------------------------------------------------------
// RoPE + L2 normalize, table-driven, in place on bf16 q/k [B,H,S,64].
// Wave handles 4 rows; lane owns 4 consecutive dims (2 rope pairs, no shfl).
// ---------------------------------------------------------------------------
__global__ __launch_bounds__(256) void rope_norm(short* __restrict__ qb,
                                                 short* __restrict__ kb,
                                                 const float* __restrict__ tab) {
  const int t = threadIdx.x;
  const int w = t >> 6;
  const int lane = t & 63;
  const int r = blockIdx.x * 16 + w * 4 + (lane >> 4);  // 0..2*BHS-1
  short* buf = (r < BHS) ? qb : kb;
  const int row = r & (BHS - 1);
  const int s = row & 2047;
  const int c4 = (lane & 15) * 4;                       // dims c4..c4+3
  short* p = buf + (long)row * 64 + c4;
  const bf16x4 x4 = *(const bf16x4*)p;
  const float x0 = bf2f(x4[0]), x1 = bf2f(x4[1]);
  const float x2 = bf2f(x4[2]), x3 = bf2f(x4[3]);
  const int f0 = c4 >> 1;                               // even
  const float4 tc = *(const float4*)&tab[s * 64 + f0 * 2];  // sin0,cos0,sin1,cos1
  const float e0 = x0 * tc.y - x1 * tc.x;
  const float o0 = x0 * tc.x + x1 * tc.y;
  const float e1 = x2 * tc.w - x3 * tc.z;
  const float o1 = x2 * tc.z + x3 * tc.w;
  float ss = e0 * e0 + o0 * o0 + e1 * e1 + o1 * o1;
  ss += __shfl_xor(ss, 1, 64);
  ss += __shfl_xor(ss, 2, 64);
  ss += __shfl_xor(ss, 4, 64);
  ss += __shfl_xor(ss, 8, 64);
  const float sc = 1.0f / fmaxf(sqrtf(ss), 1e-12f);
  short o[4] = {f2bf(e0 * sc), f2bf(o0 * sc), f2bf(e1 * sc), f2bf(o1 * sc)};
  *(bf16x4*)p = *(const bf16x4*)o;
}

// ---------------------------------------------------------------------------
// MFMA streaming attention (scores in [-1/8,1/8] => no max subtraction).
// Block = 4 waves x 32 q-rows = 128 q-rows. 64-key K/V tiles staged via
// global_load_lds in FRAGMENT-CONTIGUOUS order: slot(nt,h,cc,qq) =
// nt*128+h*64+cc*4+qq holds K[nt*16+cc][16B-chunk 4h+qq]; every ds_read_b128
// covers 64 consecutive slots (conflict-free). P uses the same slot scheme
// with row-coding rs=r*4+quad so scalar stores are <=2-way.
// ---------------------------------------------------------------------------
__global__ __launch_bounds__(256) void attn_mfma(
    const short* __restrict__ qb,  // [B,H,S,64]
    const short* __restrict__ kb,  // [B,H,S,64]
    const short* __restrict__ vt,  // [B,H,64,S]
    short* __restrict__ ob) {      // [B,H,S,64]
  __shared__ short Kf[4096];       // 512 slots * 8 shorts
  __shared__ short Vf[4096];
  __shared__ short Pf[4][2048];    // per wave: 256 slots (32q x 64k)
  const int t = threadIdx.x;
  const int w = t >> 6;
  const int lane = t & 63;
  const int col = lane & 15;
  const int quad = lane >> 4;
  const int pc = ((col & 3) << 2) | (col >> 2);   // pi(col) row decode
  const int bh = blockIdx.y;
  const int q0 = blockIdx.x * 128;
  const long hb = (long)bh * S_ * 64;             // shorts
  const short* kg = kb + hb;
  const short* vg = vt + (long)bh * 64 * S_;

  // Q fragments: rows q0 + w*32 + mt2*16 + col, dims h*32 + quad*8 + j
  bf16x8 qa[2][2];
#pragma unroll
  for (int mt2 = 0; mt2 < 2; mt2++)
#pragma unroll
    for (int h = 0; h < 2; h++)
      qa[mt2][h] = *(const bf16x8*)&qb[hb + (long)(q0 + w * 32 + mt2 * 16 + col) * 64 +
                                       h * 32 + quad * 8];

  // staging slot decode for this thread (slots t and t+256)
  const int s1 = t, s2 = t + 256;
  const int nt1 = s1 >> 7, h1 = (s1 >> 6) & 1, cc1 = (s1 >> 2) & 15, qq1 = s1 & 3;
  const int nt2 = s2 >> 7, h2 = (s2 >> 6) & 1, cc2 = (s2 >> 2) & 15, qq2 = s2 & 3;
  const int kofs1 = (nt1 * 16 + cc1) * 64 + (h1 * 4 + qq1) * 8;  // K row offset
  const int kofs2 = (nt2 * 16 + cc2) * 64 + (h2 * 4 + qq2) * 8;
  const int vofs1 = (nt1 * 16 + cc1) * 2048 + (h1 * 4 + qq1) * 8; // V^T row ofs
  const int vofs2 = (nt2 * 16 + cc2) * 2048 + (h2 * 4 + qq2) * 8;

  f32x4 oacc[2][4] = {};
  float lsum[2][4] = {};
  short* Pw = &Pf[w][0];

  for (int kt = 0; kt < S_; kt += 64) {
    __syncthreads();
    gload_lds16(kg + (long)kt * 64 + kofs1, Kf + w * 512);
    gload_lds16(kg + (long)kt * 64 + kofs2, Kf + 2048 + w * 512);
    gload_lds16(vg + kt + vofs1, Vf + w * 512);
    gload_lds16(vg + kt + vofs2, Vf + 2048 + w * 512);
    __syncthreads();

    // S = Q K^T : 2 m-tiles x 4 key-tiles
    f32x4 sc[2][4] = {};
#pragma unroll
    for (int nt = 0; nt < 4; nt++) {
      const bf16x8 kb0 = *(const bf16x8*)&Kf[nt * 1024 + col * 32 + quad * 8];
      const bf16x8 kb1 = *(const bf16x8*)&Kf[nt * 1024 + 512 + col * 32 + quad * 8];
#pragma unroll
      for (int mt2 = 0; mt2 < 2; mt2++) {
        sc[mt2][nt] = __builtin_amdgcn_mfma_f32_16x16x32_bf16(
            qa[mt2][0], kb0, sc[mt2][nt], 0, 0, 0);
        sc[mt2][nt] = __builtin_amdgcn_mfma_f32_16x16x32_bf16(
            qa[mt2][1], kb1, sc[mt2][nt], 0, 0, 0);
      }
    }

    // exp + row-sums + P store (fragment-order, rs = r*4+quad row coding)
#pragma unroll
    for (int mt2 = 0; mt2 < 2; mt2++)
#pragma unroll
      for (int nt = 0; nt < 4; nt++) {
        const int kbase = (nt >> 1) * 512 + ((nt * 2 + (col >> 3)) & 3) * 8 + (col & 7);
#pragma unroll
        for (int r = 0; r < 4; r++) {
          const float e = __expf(sc[mt2][nt][r] * 0.125f);
          lsum[mt2][r] += e;
          Pw[mt2 * 1024 + kbase + (r * 4 + quad) * 32] = f2bf(e);
        }
      }

    // P A-fragments (wave-private LDS round trip)
    bf16x8 pa[2][2];
#pragma unroll
    for (int mt2 = 0; mt2 < 2; mt2++)
#pragma unroll
      for (int h = 0; h < 2; h++)
        pa[mt2][h] = *(const bf16x8*)&Pw[mt2 * 1024 + h * 512 + pc * 32 + quad * 8];

    // O += P V : B-fragments from Vf
#pragma unroll
    for (int nt = 0; nt < 4; nt++) {
      const bf16x8 vb0 = *(const bf16x8*)&Vf[nt * 1024 + col * 32 + quad * 8];
      const bf16x8 vb1 = *(const bf16x8*)&Vf[nt * 1024 + 512 + col * 32 + quad * 8];
#pragma unroll
      for (int mt2 = 0; mt2 < 2; mt2++) {
        oacc[mt2][nt] = __builtin_amdgcn_mfma_f32_16x16x32_bf16(
            pa[mt2][0], vb0, oacc[mt2][nt], 0, 0, 0);
        oacc[mt2][nt] = __builtin_amdgcn_mfma_f32_16x16x32_bf16(
            pa[mt2][1], vb1, oacc[mt2][nt], 0, 0, 0);
      }
    }
  }

  // finish row sums (16 col-lanes per quad hold partial sums of same rows)
#pragma unroll
  for (int mt2 = 0; mt2 < 2; mt2++)
#pragma unroll
    for (int r = 0; r < 4; r++) {
      float s = lsum[mt2][r];
      s += __shfl_xor(s, 1, 64);
      s += __shfl_xor(s, 2, 64);
      s += __shfl_xor(s, 4, 64);
      s += __shfl_xor(s, 8, 64);
      lsum[mt2][r] = s;
    }

#pragma unroll
  for (int mt2 = 0; mt2 < 2; mt2++)
#pragma unroll
    for (int r = 0; r < 4; r++) {
      const float inv = 1.0f / lsum[mt2][r];
      const long base = hb + (long)(q0 + w * 32 + mt2 * 16 + quad * 4 + r) * 64;
#pragma unroll
      for (int nt = 0; nt < 4; nt++)
        ob[base + nt * 16 + col] = f2bf(oacc[mt2][nt][r] * inv);
    }
}

// ---------------------------------------------------------------------------
// out projection: A = O bf16 [B,H,S,64] (k -> (h,hd) remap in staging),
// W = out_w bf16 [1024,1024]. fp32 out + bias.
// ---------------------------------------------------------------------------
__global__ __launch_bounds__(256) void out_mfma(
    const short* __restrict__ O, const short* __restrict__ W,
    const float* __restrict__ bias, float* __restrict__ out) {
  __shared__ short As[128 * 32];
  __shared__ short Bs[128 * 32];
  const int t = threadIdx.x;
  const int w = t >> 6;
  const int lane = t & 63;
  const int col = lane & 15;
  const int quad = lane >> 4;
  const int wm = w >> 1;
  const int wn = w & 1;
  const int m0 = blockIdx.y * 128;
  const int n0 = blockIdx.x * 128;

  f32x4 acc[4][4] = {};

  for (int k0 = 0; k0 < 1024; k0 += 32) {
    __syncthreads();
#pragma unroll
    for (int i = 0; i < 2; i++) {
      const int c = w * 2 + i;
      const int sl = c * 64 + lane;
      const int row = sl >> 2;
      const int gseg = (sl & 3) ^ (row & 3);
      const int n = m0 + row;
      const int bidx = n >> 11;
      const int s = n & 2047;
      const int kk = k0 + gseg * 8;
      const int h = kk >> 6;
      const int hd = kk & 63;
      gload_lds16(&O[((long)(bidx * 16 + h) * 2048 + s) * 64 + hd],
                  As + c * 512);
      gload_lds16(&W[(n0 + row) * 1024 + k0 + gseg * 8], Bs + c * 512);
    }
    __syncthreads();

    bf16x8 af[4], bf[4];
#pragma unroll
    for (int mt = 0; mt < 4; mt++) {
      const int m = wm * 64 + mt * 16 + col;
      af[mt] = *(const bf16x8*)&As[m * 32 + ((quad ^ (m & 3)) * 8)];
    }
#pragma unroll
    for (int nt = 0; nt < 4; nt++) {
      const int n = wn * 64 + nt * 16 + col;
      bf[nt] = *(const bf16x8*)&Bs[n * 32 + ((quad ^ (n & 3)) * 8)];
    }
#pragma unroll
    for (int mt = 0; mt < 4; mt++)
#pragma unroll
      for (int nt = 0; nt < 4; nt++)
        acc[mt][nt] = __builtin_amdgcn_mfma_f32_16x16x32_bf16(
            af[mt], bf[nt], acc[mt][nt], 0, 0, 0);
  }

  float bi[4];
#pragma unroll
  for (int nt = 0; nt < 4; nt++) bi[nt] = bias[n0 + wn * 64 + nt * 16 + col];
#pragma unroll
  for (int mt = 0; mt < 4; mt++) {
#pragma unroll
    for (int r = 0; r < 4; r++) {
      const int n = m0 + wm * 64 + mt * 16 + quad * 4 + r;
#pragma unroll
      for (int nt = 0; nt < 4; nt++)
        out[(long)n * 1024 + n0 + wn * 64 + nt * 16 + col] =
            acc[mt][nt][r] + bi[nt];
    }
  }
}

// ---------------------------------------------------------------------------
extern "C" void kernel_launch(void* const* d_in, const int* in_sizes, int n_in,
                              void* d_out, int out_size, void* d_ws,
                              size_t ws_size, hipStream_t stream) {
  const float* tokens = (const float*)d_in[0];
  const float* qkv_w = (const float*)d_in[1];
  const float* qkv_b = (const float*)d_in[2];
  const float* out_w = (const float*)d_in[3];
  const float* out_b = (const float*)d_in[4];
  float* out = (float*)d_out;

  const size_t per = (size_t)BHS * HD_;          // 4,194,304 elements
  float* tab = (float*)d_ws;                     // 2048*32*2 floats = 512 KB
  short* tok_bf = (short*)(tab + 2048 * 64);
  short* qkvw_bf = tok_bf + per;                 // 3M shorts
  short* outw_bf = qkvw_bf + 3 * per / 4;        // 1M
  short* q_bf = outw_bf + per / 4;               // 4M
  short* k_bf = q_bf + per;                      // 4M
  short* vt_bf = k_bf + per;                     // 4M
  short* O_bf = vt_bf + per;                     // 4M  (~48.5 MB total)

  // 1) casts + rope table
  hipLaunchKernelGGL(prep, dim3(4128), dim3(256), 0, stream, tokens, qkv_w,
                     out_w, tok_bf, qkvw_bf, outw_bf, tab);
  // 2) QKV projection -> q/k [B,H,S,64] + vt [B,H,64,S] (fused transpose)
  hipLaunchKernelGGL(qkv_mfma, dim3(24, 32), dim3(256), 0, stream, tok_bf,
                     qkvw_bf, qkv_b, q_bf, k_bf, vt_bf);
  // 3) RoPE + normalize (in place, table-driven)
  hipLaunchKernelGGL(rope_norm, dim3(2 * BHS / 16), dim3(256), 0, stream,
                     q_bf, k_bf, tab);
  // 4) Attention
  hipLaunchKernelGGL(attn_mfma, dim3(S_ / 128, B_ * H_), dim3(256), 0, stream,
                     q_bf, k_bf, vt_bf, O_bf);
  // 5) Output projection
  hipLaunchKernelGGL(out_mfma, dim3(8, 32), dim3(256), 0, stream, O_bf,
                     outw_bf, out_b, out);
}

// Round 5
// 223.322 us; speedup vs baseline: 13.9914x; 1.0463x over previous
//
#include <hip/hip_runtime.h>
#include <hip/hip_bf16.h>
#include <math.h>

// Problem constants
#define B_ 2
#define S_ 2048
#define D_ 1024
#define H_ 16
#define HD_ 64
#define BHS (B_*H_*S_)          // 65536 rows of [HD]
#define NROWS (B_*S_)           // 4096 token rows

typedef __attribute__((ext_vector_type(8))) short bf16x8;
typedef __attribute__((ext_vector_type(4))) float f32x4;

__device__ __forceinline__ short f2bf(float x) {
  __hip_bfloat16 h = __float2bfloat16(x);
  return *reinterpret_cast<short*>(&h);
}
__device__ __forceinline__ int pack2bf(float lo, float hi) {
  return (int)(((unsigned)(unsigned short)f2bf(hi) << 16) |
               (unsigned)(unsigned short)f2bf(lo));
}

// async 16B global -> LDS (hardware adds lane*16 to the wave-uniform base)
__device__ __forceinline__ void gload_lds16(const short* g, short* l) {
  __builtin_amdgcn_global_load_lds(
      (const __attribute__((address_space(1))) void*)g,
      (__attribute__((address_space(3))) void*)l, 16, 0, 0);
}

// ---------------------------------------------------------------------------
// prep: fused fp32->bf16 casts (tokens, qkv_w, out_w) + RoPE sin/cos table.
// ---------------------------------------------------------------------------
__global__ __launch_bounds__(256) void prep(
    const float* __restrict__ tokens, const float* __restrict__ qkv_w,
    const float* __restrict__ out_w, short* __restrict__ tok_bf,
    short* __restrict__ qkvw_bf, short* __restrict__ outw_bf,
    float* __restrict__ tab) {
  const int i = blockIdx.x * 256 + threadIdx.x;
  const float* src;
  short* dst;
  int j;
  if (i < 524288) {
    src = tokens; dst = tok_bf; j = i;
  } else if (i < 917504) {
    src = qkv_w; dst = qkvw_bf; j = i - 524288;
  } else if (i < 1048576) {
    src = out_w; dst = outw_bf; j = i - 917504;
  } else if (i < 1056768) {
    const int e = (i - 1048576) * 8;     // entry = s*32 + f
    const int s = e >> 5;
    const int f0 = e & 31;
#pragma unroll
    for (int k = 0; k < 8; k++) {
      const int f = f0 + k;
      const float theta = (float)s * exp2f(-(float)f * 0.41524101186092034f);
      float sn, cs;
      sincosf(theta, &sn, &cs);
      tab[(s * 32 + f) * 2] = sn;
      tab[(s * 32 + f) * 2 + 1] = cs;
    }
    return;
  } else {
    return;
  }
  const float4 a = *(const float4*)(src + (long)j * 8);
  const float4 b = *(const float4*)(src + (long)j * 8 + 4);
  short tmp[8] = {f2bf(a.x), f2bf(a.y), f2bf(a.z), f2bf(a.w),
                  f2bf(b.x), f2bf(b.y), f2bf(b.z), f2bf(b.w)};
  *(bf16x8*)(dst + (long)j * 8) = *(const bf16x8*)tmp;
}

// ---------------------------------------------------------------------------
// qkv projection: bf16 MFMA GEMM 128x128, BK=32, 4 waves. Fused epilogues:
//   q/k heads: RoPE (pairs = neighbor lanes, shfl_xor 1) + L2 norm, bf16 out.
//   v heads: per-wave LDS transpose -> vt [B,H,64,S].
// Tv overlays As/Bs (union smem) => 34.8 KB LDS, 4 blocks/CU.
// ---------------------------------------------------------------------------
__global__ __launch_bounds__(256) void qkv_mfma(
    const short* __restrict__ A, const short* __restrict__ W,
    const float* __restrict__ bias, const float* __restrict__ tab,
    short* __restrict__ qb, short* __restrict__ kb, short* __restrict__ vtb) {
  __shared__ short smem[17408];   // As[4096] | Bs[4096] ; Tv = 4 x 4352 overlay
  short* As = smem;
  short* Bs = smem + 4096;
  const int t = threadIdx.x;
  const int w = t >> 6;
  const int lane = t & 63;
  const int col = lane & 15;
  const int quad = lane >> 4;
  const int wm = w >> 1;
  const int wn = w & 1;
  const int m0 = blockIdx.y * 128;
  const int n0 = blockIdx.x * 128;

  f32x4 acc[4][4] = {};

  for (int k0 = 0; k0 < 1024; k0 += 32) {
    __syncthreads();
#pragma unroll
    for (int i = 0; i < 2; i++) {
      const int c = w * 2 + i;
      const int sl = c * 64 + lane;
      const int row = sl >> 2;
      const int gseg = (sl & 3) ^ (row & 3);
      gload_lds16(&A[(m0 + row) * 1024 + k0 + gseg * 8], As + c * 512);
      gload_lds16(&W[(n0 + row) * 1024 + k0 + gseg * 8], Bs + c * 512);
    }
    __syncthreads();

    bf16x8 af[4], bfr[4];
#pragma unroll
    for (int mt = 0; mt < 4; mt++) {
      const int m = wm * 64 + mt * 16 + col;
      af[mt] = *(const bf16x8*)&As[m * 32 + ((quad ^ (m & 3)) * 8)];
    }
#pragma unroll
    for (int nt = 0; nt < 4; nt++) {
      const int n = wn * 64 + nt * 16 + col;
      bfr[nt] = *(const bf16x8*)&Bs[n * 32 + ((quad ^ (n & 3)) * 8)];
    }
#pragma unroll
    for (int mt = 0; mt < 4; mt++)
#pragma unroll
      for (int nt = 0; nt < 4; nt++)
        acc[mt][nt] = __builtin_amdgcn_mfma_f32_16x16x32_bf16(
            af[mt], bfr[nt], acc[mt][nt], 0, 0, 0);
  }

  const int j_base = n0 + wn * 64;    // 64-aligned -> single (c, h); uniform/block
  const int c = j_base >> 10;
  const int h = (j_base >> 6) & 15;
  float bi[4];
#pragma unroll
  for (int nt = 0; nt < 4; nt++) bi[nt] = bias[j_base + nt * 16 + col];

  if (c < 2) {
    // ---- q/k: fused RoPE + L2 normalize ----
    short* dst = (c == 0) ? qb : kb;
#pragma unroll
    for (int mt = 0; mt < 4; mt++) {
#pragma unroll
      for (int r = 0; r < 4; r++) {
        const int n = m0 + wm * 64 + mt * 16 + quad * 4 + r;
        const int bidx = n >> 11;
        const int s = n & 2047;
        float rot[4];
        float ss = 0.0f;
#pragma unroll
        for (int nt = 0; nt < 4; nt++) {
          const float x = acc[mt][nt][r] + bi[nt];
          const int f = (nt * 16 + col) >> 1;
          const float2 sc2 = *(const float2*)&tab[(s * 32 + f) * 2];
          const float partner = __shfl_xor(x, 1, 64);
          rot[nt] = fmaf(partner, (col & 1) ? sc2.x : -sc2.x, x * sc2.y);
          ss += rot[nt] * rot[nt];
        }
        ss += __shfl_xor(ss, 1, 64);
        ss += __shfl_xor(ss, 2, 64);
        ss += __shfl_xor(ss, 4, 64);
        ss += __shfl_xor(ss, 8, 64);
        const float scl = 1.0f / fmaxf(sqrtf(ss), 1e-12f);
        const long base = ((long)(bidx * 16 + h) * 2048 + s) * 64;
#pragma unroll
        for (int nt = 0; nt < 4; nt++)
          dst[base + nt * 16 + col] = f2bf(rot[nt] * scl);
      }
    }
  } else {
    // ---- v: per-wave 64x64 (s,d) tile -> LDS -> transposed store ----
    __syncthreads();                   // all waves done with As/Bs
    short* T = smem + w * 4352;        // 64 x 68
#pragma unroll
    for (int mt = 0; mt < 4; mt++)
#pragma unroll
      for (int r = 0; r < 4; r++)
#pragma unroll
        for (int nt = 0; nt < 4; nt++)
          T[(mt * 16 + quad * 4 + r) * 68 + nt * 16 + col] =
              f2bf(acc[mt][nt][r] + bi[nt]);
    const int bidx = (m0 + wm * 64) >> 11;
    const int s0 = (m0 + wm * 64) & 2047;
#pragma unroll
    for (int pass = 0; pass < 4; pass++) {
      const int d = pass * 16 + (lane >> 2);
      const int ks = (lane & 3) * 16;
      short tmp[16];
#pragma unroll
      for (int j = 0; j < 16; j++) tmp[j] = T[(ks + j) * 68 + d];
      short* dstp = vtb + ((long)(bidx * 16 + h) * 64 + d) * 2048 + s0 + ks;
      *(bf16x8*)dstp = *(const bf16x8*)tmp;
      *(bf16x8*)(dstp + 8) = *(const bf16x8*)(tmp + 8);
    }
  }
}

// ---------------------------------------------------------------------------
// MFMA streaming attention, S^T formulation (no max subtraction needed:
// unit q,k => |score| <= 1/8).  Per wave: 32 q-rows (mt2 tiles of 16).
// S^T = mfma(K-frag, Q-frag): C-layout gives each lane 4 CONSECUTIVE keys of
// one q => exp'd P packs to dwords in-register, dumped with 4 lane-contiguous
// b128 stores (2-way, free) and read back as b64 P^T B-fragments.
// O^T = mfma(V^T-frag, P^T-frag); epilogue transposes O^T via per-wave LDS.
// ---------------------------------------------------------------------------
__global__ __launch_bounds__(256) void attn_mfma(
    const short* __restrict__ qb,  // [B,H,S,64]
    const short* __restrict__ kb,  // [B,H,S,64]
    const short* __restrict__ vt,  // [B,H,64,S]
    short* __restrict__ ob) {      // [B,H,S,64]
  __shared__ short Kf[4096];       // 512 slots * 8 shorts (frag-contiguous)
  __shared__ short Vf[4096];
  __shared__ int Pd[4][1280];      // per-wave: 64 lanes x 20 dwords
  const int t = threadIdx.x;
  const int w = t >> 6;
  const int lane = t & 63;
  const int col = lane & 15;
  const int quad = lane >> 4;
  const int bh = blockIdx.x;       // bh on x: consecutive blocks spread bh
  const int q0 = blockIdx.y * 128; //   across XCDs -> per-XCD K/V L2 locality
  const long hb = (long)bh * S_ * 64;
  const short* kg = kb + hb;
  const short* vg = vt + (long)bh * 64 * S_;

  // Q B-fragments: B[k=dim][n=q]: rows q0+w*32+mt2*16+col, dims h*32+quad*8+j
  bf16x8 qa[2][2];
#pragma unroll
  for (int mt2 = 0; mt2 < 2; mt2++)
#pragma unroll
    for (int h = 0; h < 2; h++)
      qa[mt2][h] = *(const bf16x8*)&qb[hb +
          (long)(q0 + w * 32 + mt2 * 16 + col) * 64 + h * 32 + quad * 8];

  // staging slot decode (slots t and t+256), fragment-contiguous order
  const int s1 = t, s2 = t + 256;
  const int nt1 = s1 >> 7, h1 = (s1 >> 6) & 1, cc1 = (s1 >> 2) & 15, qq1 = s1 & 3;
  const int nt2 = s2 >> 7, h2 = (s2 >> 6) & 1, cc2 = (s2 >> 2) & 15, qq2 = s2 & 3;
  const int kofs1 = (nt1 * 16 + cc1) * 64 + (h1 * 4 + qq1) * 8;
  const int kofs2 = (nt2 * 16 + cc2) * 64 + (h2 * 4 + qq2) * 8;
  const int vofs1 = (nt1 * 16 + cc1) * 2048 + (h1 * 4 + qq1) * 8;
  const int vofs2 = (nt2 * 16 + cc2) * 2048 + (h2 * 4 + qq2) * 8;

  f32x4 oacc[2][4] = {};
  float lsum[2] = {0.f, 0.f};
  int* Pw = &Pd[w][0];

  for (int kt = 0; kt < S_; kt += 64) {
    __syncthreads();
    gload_lds16(kg + (long)kt * 64 + kofs1, Kf + w * 512);
    gload_lds16(kg + (long)kt * 64 + kofs2, Kf + 2048 + w * 512);
    gload_lds16(vg + kt + vofs1, Vf + w * 512);
    gload_lds16(vg + kt + vofs2, Vf + 2048 + w * 512);
    __syncthreads();

    // S^T = K Q^T : C[m=key][n=q], per nt-tile of 16 keys
    f32x4 sc[2][4];
#pragma unroll
    for (int nt = 0; nt < 4; nt++) {
      const bf16x8 ka0 = *(const bf16x8*)&Kf[nt * 1024 + col * 32 + quad * 8];
      const bf16x8 ka1 = *(const bf16x8*)&Kf[nt * 1024 + 512 + col * 32 + quad * 8];
#pragma unroll
      for (int mt2 = 0; mt2 < 2; mt2++) {
        f32x4 z = {0.f, 0.f, 0.f, 0.f};
        z = __builtin_amdgcn_mfma_f32_16x16x32_bf16(ka0, qa[mt2][0], z, 0, 0, 0);
        sc[mt2][nt] =
            __builtin_amdgcn_mfma_f32_16x16x32_bf16(ka1, qa[mt2][1], z, 0, 0, 0);
      }
    }

    // exp + row-sum + packed dump (lane holds keys quad*4+r of q=col)
#pragma unroll
    for (int mt2 = 0; mt2 < 2; mt2++) {
      int d8[8];
#pragma unroll
      for (int nt = 0; nt < 4; nt++) {
        const float e0 = __expf(sc[mt2][nt][0] * 0.125f);
        const float e1 = __expf(sc[mt2][nt][1] * 0.125f);
        const float e2 = __expf(sc[mt2][nt][2] * 0.125f);
        const float e3 = __expf(sc[mt2][nt][3] * 0.125f);
        lsum[mt2] += (e0 + e1) + (e2 + e3);
        d8[nt * 2] = pack2bf(e0, e1);
        d8[nt * 2 + 1] = pack2bf(e2, e3);
      }
      int* dp = Pw + lane * 20 + mt2 * 8;
      *(int4*)dp = make_int4(d8[0], d8[1], d8[2], d8[3]);
      *(int4*)(dp + 4) = make_int4(d8[4], d8[5], d8[6], d8[7]);
    }

    // P^T B-fragments: lane (quad,col) needs P[q=col][g*32+quad*8+j]
    bf16x8 pb[2][2];
#pragma unroll
    for (int mt2 = 0; mt2 < 2; mt2++)
#pragma unroll
      for (int g = 0; g < 2; g++) {
        const int slA = (quad & 1) * 32 + col;
        const int nt = g * 2 + (quad >> 1);
        const int2 a = *(const int2*)(Pw + slA * 20 + mt2 * 8 + nt * 2);
        const int2 b = *(const int2*)(Pw + (slA + 16) * 20 + mt2 * 8 + nt * 2);
        int tmp4[4] = {a.x, a.y, b.x, b.y};
        pb[mt2][g] = *(const bf16x8*)tmp4;
      }

    // O^T += V^T P^T : per d-tile dt
#pragma unroll
    for (int dt = 0; dt < 4; dt++) {
      const bf16x8 va0 = *(const bf16x8*)&Vf[dt * 1024 + col * 32 + quad * 8];
      const bf16x8 va1 = *(const bf16x8*)&Vf[dt * 1024 + 512 + col * 32 + quad * 8];
#pragma unroll
      for (int mt2 = 0; mt2 < 2; mt2++) {
        oacc[mt2][dt] = __builtin_amdgcn_mfma_f32_16x16x32_bf16(
            va0, pb[mt2][0], oacc[mt2][dt], 0, 0, 0);
        oacc[mt2][dt] = __builtin_amdgcn_mfma_f32_16x16x32_bf16(
            va1, pb[mt2][1], oacc[mt2][dt], 0, 0, 0);
      }
    }
  }

  // finish denominators: sum over quads (lanes same col)
  float inv[2];
#pragma unroll
  for (int mt2 = 0; mt2 < 2; mt2++) {
    float s = lsum[mt2];
    s += __shfl_xor(s, 16, 64);
    s += __shfl_xor(s, 32, 64);
    inv[mt2] = 1.0f / s;
  }

  // epilogue: O^T (d,q) -> O (q,d) via per-wave LDS bounce, coalesced store
  short* T = (short*)Pw;               // 16 x 72
#pragma unroll
  for (int mt2 = 0; mt2 < 2; mt2++) {
#pragma unroll
    for (int dt = 0; dt < 4; dt++)
#pragma unroll
      for (int r = 0; r < 4; r++)
        T[col * 72 + dt * 16 + quad * 4 + r] = f2bf(oacc[mt2][dt][r] * inv[mt2]);
    const bf16x8 v0 = *(const bf16x8*)&T[(lane & 15) * 72 + (lane >> 4) * 16];
    const bf16x8 v1 = *(const bf16x8*)&T[(lane & 15) * 72 + (lane >> 4) * 16 + 8];
    short* orow = ob + hb +
        (long)(q0 + w * 32 + mt2 * 16 + (lane & 15)) * 64 + (lane >> 4) * 16;
    *(bf16x8*)orow = v0;
    *(bf16x8*)(orow + 8) = v1;
  }
}

// ---------------------------------------------------------------------------
// out projection: 64x128 tile (grid 512 = 2 blocks/CU), BK=32, 4 waves (2x2).
// A = O bf16 [B,H,S,64] (k -> (h,hd) remap in staging), fp32 out + bias.
// ---------------------------------------------------------------------------
__global__ __launch_bounds__(256) void out_mfma(
    const short* __restrict__ O, const short* __restrict__ W,
    const float* __restrict__ bias, float* __restrict__ out) {
  __shared__ short As[64 * 32];    // 256 x 16B chunks
  __shared__ short Bs[128 * 32];   // 512 chunks
  const int t = threadIdx.x;
  const int w = t >> 6;
  const int lane = t & 63;
  const int col = lane & 15;
  const int quad = lane >> 4;
  const int wm = w >> 1;
  const int wn = w & 1;
  const int m0 = blockIdx.y * 64;
  const int n0 = blockIdx.x * 128;

  f32x4 acc[2][4] = {};

  for (int k0 = 0; k0 < 1024; k0 += 32) {
    __syncthreads();
    {
      // As: one chunk per thread
      const int row = t >> 2;
      const int gseg = (t & 3) ^ (row & 3);
      const int n = m0 + row;
      const int bidx = n >> 11;
      const int s = n & 2047;
      const int kk = k0 + gseg * 8;
      gload_lds16(&O[((long)(bidx * 16 + (kk >> 6)) * 2048 + s) * 64 + (kk & 63)],
                  As + w * 512);
    }
#pragma unroll
    for (int i = 0; i < 2; i++) {
      const int cs = w * 2 + i;
      const int sl = cs * 64 + lane;
      const int row = sl >> 2;
      const int gseg = (sl & 3) ^ (row & 3);
      gload_lds16(&W[(n0 + row) * 1024 + k0 + gseg * 8], Bs + cs * 512);
    }
    __syncthreads();

    bf16x8 af[2], bfr[4];
#pragma unroll
    for (int mt = 0; mt < 2; mt++) {
      const int m = wm * 32 + mt * 16 + col;
      af[mt] = *(const bf16x8*)&As[m * 32 + ((quad ^ (m & 3)) * 8)];
    }
#pragma unroll
    for (int nt = 0; nt < 4; nt++) {
      const int n = wn * 64 + nt * 16 + col;
      bfr[nt] = *(const bf16x8*)&Bs[n * 32 + ((quad ^ (n & 3)) * 8)];
    }
#pragma unroll
    for (int mt = 0; mt < 2; mt++)
#pragma unroll
      for (int nt = 0; nt < 4; nt++)
        acc[mt][nt] = __builtin_amdgcn_mfma_f32_16x16x32_bf16(
            af[mt], bfr[nt], acc[mt][nt], 0, 0, 0);
  }

  float bi[4];
#pragma unroll
  for (int nt = 0; nt < 4; nt++) bi[nt] = bias[n0 + wn * 64 + nt * 16 + col];
#pragma unroll
  for (int mt = 0; mt < 2; mt++) {
#pragma unroll
    for (int r = 0; r < 4; r++) {
      const int n = m0 + wm * 32 + mt * 16 + quad * 4 + r;
#pragma unroll
      for (int nt = 0; nt < 4; nt++)
        out[(long)n * 1024 + n0 + wn * 64 + nt * 16 + col] =
            acc[mt][nt][r] + bi[nt];
    }
  }
}

// ---------------------------------------------------------------------------
extern "C" void kernel_launch(void* const* d_in, const int* in_sizes, int n_in,
                              void* d_out, int out_size, void* d_ws,
                              size_t ws_size, hipStream_t stream) {
  const float* tokens = (const float*)d_in[0];
  const float* qkv_w = (const float*)d_in[1];
  const float* qkv_b = (const float*)d_in[2];
  const float* out_w = (const float*)d_in[3];
  const float* out_b = (const float*)d_in[4];
  float* out = (float*)d_out;

  const size_t per = (size_t)BHS * HD_;          // 4,194,304 elements
  float* tab = (float*)d_ws;                     // 2048*32*2 floats = 512 KB
  short* tok_bf = (short*)(tab + 2048 * 64);
  short* qkvw_bf = tok_bf + per;                 // 3M shorts
  short* outw_bf = qkvw_bf + 3 * per / 4;        // 1M
  short* q_bf = outw_bf + per / 4;               // 4M
  short* k_bf = q_bf + per;                      // 4M
  short* vt_bf = k_bf + per;                     // 4M
  short* O_bf = vt_bf + per;                     // 4M  (~48.5 MB total)

  // 1) casts + rope table
  hipLaunchKernelGGL(prep, dim3(4128), dim3(256), 0, stream, tokens, qkv_w,
                     out_w, tok_bf, qkvw_bf, outw_bf, tab);
  // 2) QKV projection + fused RoPE/norm (q,k) + fused V transpose
  hipLaunchKernelGGL(qkv_mfma, dim3(24, 32), dim3(256), 0, stream, tok_bf,
                     qkvw_bf, qkv_b, tab, q_bf, k_bf, vt_bf);
  // 3) Attention (S^T formulation)
  hipLaunchKernelGGL(attn_mfma, dim3(B_ * H_, S_ / 128), dim3(256), 0, stream,
                     q_bf, k_bf, vt_bf, O_bf);
  // 4) Output projection
  hipLaunchKernelGGL(out_mfma, dim3(8, 64), dim3(256), 0, stream, O_bf,
                     outw_bf, out_b, out);
}

// Round 7
// 214.395 us; speedup vs baseline: 14.5740x; 1.0416x over previous
//
#include <hip/hip_runtime.h>
#include <hip/hip_bf16.h>
#include <math.h>

// Problem constants
#define B_ 2
#define S_ 2048
#define D_ 1024
#define H_ 16
#define HD_ 64
#define BHS (B_*H_*S_)          // 65536 rows of [HD]
#define NROWS (B_*S_)           // 4096 token rows

typedef __attribute__((ext_vector_type(8))) short bf16x8;
typedef __attribute__((ext_vector_type(4))) short bf16x4;
typedef __attribute__((ext_vector_type(4))) float f32x4;

// 16x16x16 bf16 MFMA. NOTE: gate on __HIP_DEVICE_COMPILE__, NOT bare
// __has_builtin — amdgcn builtins are callable but not __has_builtin-visible
// in the host pass (host only needs to typecheck device code).
#ifdef __HIP_DEVICE_COMPILE__
#if __has_builtin(__builtin_amdgcn_mfma_f32_16x16x16bf16_1k)
#define MFMA16(a, b, c) __builtin_amdgcn_mfma_f32_16x16x16bf16_1k(a, b, c, 0, 0, 0)
#else
#define MFMA16(a, b, c) __builtin_amdgcn_mfma_f32_16x16x16_bf16(a, b, c, 0, 0, 0)
#endif
#else
#define MFMA16(a, b, c) (c)
#endif

__device__ __forceinline__ short f2bf(float x) {
  __hip_bfloat16 h = __float2bfloat16(x);
  return *reinterpret_cast<short*>(&h);
}
// pack two positive floats to packed bf16 pair with round-half-up: 3 VALU ops
__device__ __forceinline__ int packbf_hu(float lo, float hi) {
  unsigned lb = __float_as_uint(lo) + 0x8000u;
  unsigned hb = __float_as_uint(hi) + 0x8000u;
  return (int)__builtin_amdgcn_perm(hb, lb, 0x07060302u);
}

// async 16B global -> LDS (hardware adds lane*16 to the wave-uniform base)
__device__ __forceinline__ void gload_lds16(const short* g, short* l) {
  __builtin_amdgcn_global_load_lds(
      (const __attribute__((address_space(1))) void*)g,
      (__attribute__((address_space(3))) void*)l, 16, 0, 0);
}

// ---------------------------------------------------------------------------
// prep: fused fp32->bf16 casts (tokens, qkv_w, out_w) + RoPE sin/cos table.
// ---------------------------------------------------------------------------
__global__ __launch_bounds__(256) void prep(
    const float* __restrict__ tokens, const float* __restrict__ qkv_w,
    const float* __restrict__ out_w, short* __restrict__ tok_bf,
    short* __restrict__ qkvw_bf, short* __restrict__ outw_bf,
    float* __restrict__ tab) {
  const int i = blockIdx.x * 256 + threadIdx.x;
  const float* src;
  short* dst;
  int j;
  if (i < 524288) {
    src = tokens; dst = tok_bf; j = i;
  } else if (i < 917504) {
    src = qkv_w; dst = qkvw_bf; j = i - 524288;
  } else if (i < 1048576) {
    src = out_w; dst = outw_bf; j = i - 917504;
  } else if (i < 1056768) {
    const int e = (i - 1048576) * 8;     // entry = s*32 + f
    const int s = e >> 5;
    const int f0 = e & 31;
#pragma unroll
    for (int k = 0; k < 8; k++) {
      const int f = f0 + k;
      const float theta = (float)s * exp2f(-(float)f * 0.41524101186092034f);
      float sn, cs;
      sincosf(theta, &sn, &cs);
      tab[(s * 32 + f) * 2] = sn;
      tab[(s * 32 + f) * 2 + 1] = cs;
    }
    return;
  } else {
    return;
  }
  const float4 a = *(const float4*)(src + (long)j * 8);
  const float4 b = *(const float4*)(src + (long)j * 8 + 4);
  short tmp[8] = {f2bf(a.x), f2bf(a.y), f2bf(a.z), f2bf(a.w),
                  f2bf(b.x), f2bf(b.y), f2bf(b.z), f2bf(b.w)};
  *(bf16x8*)(dst + (long)j * 8) = *(const bf16x8*)tmp;
}

// ---------------------------------------------------------------------------
// qkv projection: bf16 MFMA GEMM 128x128, BK=32, 4 waves. Fused epilogues:
//   q/k heads: RoPE (pairs = neighbor lanes, shfl_xor 1) + L2 norm, bf16 out.
//   v heads: per-wave LDS transpose -> vt [B,H,64,S].
// ---------------------------------------------------------------------------
__global__ __launch_bounds__(256) void qkv_mfma(
    const short* __restrict__ A, const short* __restrict__ W,
    const float* __restrict__ bias, const float* __restrict__ tab,
    short* __restrict__ qb, short* __restrict__ kb, short* __restrict__ vtb) {
  __shared__ short smem[17408];   // As[4096] | Bs[4096] ; Tv = 4 x 4352 overlay
  short* As = smem;
  short* Bs = smem + 4096;
  const int t = threadIdx.x;
  const int w = t >> 6;
  const int lane = t & 63;
  const int col = lane & 15;
  const int quad = lane >> 4;
  const int wm = w >> 1;
  const int wn = w & 1;
  const int m0 = blockIdx.y * 128;
  const int n0 = blockIdx.x * 128;

  f32x4 acc[4][4] = {};

  for (int k0 = 0; k0 < 1024; k0 += 32) {
    __syncthreads();
#pragma unroll
    for (int i = 0; i < 2; i++) {
      const int c = w * 2 + i;
      const int sl = c * 64 + lane;
      const int row = sl >> 2;
      const int gseg = (sl & 3) ^ (row & 3);
      gload_lds16(&A[(m0 + row) * 1024 + k0 + gseg * 8], As + c * 512);
      gload_lds16(&W[(n0 + row) * 1024 + k0 + gseg * 8], Bs + c * 512);
    }
    __syncthreads();

    bf16x8 af[4], bfr[4];
#pragma unroll
    for (int mt = 0; mt < 4; mt++) {
      const int m = wm * 64 + mt * 16 + col;
      af[mt] = *(const bf16x8*)&As[m * 32 + ((quad ^ (m & 3)) * 8)];
    }
#pragma unroll
    for (int nt = 0; nt < 4; nt++) {
      const int n = wn * 64 + nt * 16 + col;
      bfr[nt] = *(const bf16x8*)&Bs[n * 32 + ((quad ^ (n & 3)) * 8)];
    }
#pragma unroll
    for (int mt = 0; mt < 4; mt++)
#pragma unroll
      for (int nt = 0; nt < 4; nt++)
        acc[mt][nt] = __builtin_amdgcn_mfma_f32_16x16x32_bf16(
            af[mt], bfr[nt], acc[mt][nt], 0, 0, 0);
  }

  const int j_base = n0 + wn * 64;    // 64-aligned -> single (c, h); uniform/block
  const int c = j_base >> 10;
  const int h = (j_base >> 6) & 15;
  float bi[4];
#pragma unroll
  for (int nt = 0; nt < 4; nt++) bi[nt] = bias[j_base + nt * 16 + col];

  if (c < 2) {
    // ---- q/k: fused RoPE + L2 normalize ----
    short* dst = (c == 0) ? qb : kb;
#pragma unroll
    for (int mt = 0; mt < 4; mt++) {
#pragma unroll
      for (int r = 0; r < 4; r++) {
        const int n = m0 + wm * 64 + mt * 16 + quad * 4 + r;
        const int bidx = n >> 11;
        const int s = n & 2047;
        float rot[4];
        float ss = 0.0f;
#pragma unroll
        for (int nt = 0; nt < 4; nt++) {
          const float x = acc[mt][nt][r] + bi[nt];
          const int f = (nt * 16 + col) >> 1;
          const float2 sc2 = *(const float2*)&tab[(s * 32 + f) * 2];
          const float partner = __shfl_xor(x, 1, 64);
          rot[nt] = fmaf(partner, (col & 1) ? sc2.x : -sc2.x, x * sc2.y);
          ss += rot[nt] * rot[nt];
        }
        ss += __shfl_xor(ss, 1, 64);
        ss += __shfl_xor(ss, 2, 64);
        ss += __shfl_xor(ss, 4, 64);
        ss += __shfl_xor(ss, 8, 64);
        const float scl = 1.0f / fmaxf(sqrtf(ss), 1e-12f);
        const long base = ((long)(bidx * 16 + h) * 2048 + s) * 64;
#pragma unroll
        for (int nt = 0; nt < 4; nt++)
          dst[base + nt * 16 + col] = f2bf(rot[nt] * scl);
      }
    }
  } else {
    // ---- v: per-wave 64x64 (s,d) tile -> LDS -> transposed store ----
    __syncthreads();                   // all waves done with As/Bs
    short* T = smem + w * 4352;        // 64 x 68
#pragma unroll
    for (int mt = 0; mt < 4; mt++)
#pragma unroll
      for (int r = 0; r < 4; r++)
#pragma unroll
        for (int nt = 0; nt < 4; nt++)
          T[(mt * 16 + quad * 4 + r) * 68 + nt * 16 + col] =
              f2bf(acc[mt][nt][r] + bi[nt]);
    const int bidx = (m0 + wm * 64) >> 11;
    const int s0 = (m0 + wm * 64) & 2047;
#pragma unroll
    for (int pass = 0; pass < 4; pass++) {
      const int d = pass * 16 + (lane >> 2);
      const int ks = (lane & 3) * 16;
      short tmp[16];
#pragma unroll
      for (int j = 0; j < 16; j++) tmp[j] = T[(ks + j) * 68 + d];
      short* dstp = vtb + ((long)(bidx * 16 + h) * 64 + d) * 2048 + s0 + ks;
      *(bf16x8*)dstp = *(const bf16x8*)tmp;
      *(bf16x8*)(dstp + 8) = *(const bf16x8*)(tmp + 8);
    }
  }
}

// ---------------------------------------------------------------------------
// MFMA streaming attention, S^T formulation, in-register P.
// Block = 512 threads = 8 waves = 2 key-groups x 4 waves; q-tile 128/block,
// each wave owns 32 q-rows; group g covers keys [g*1024, g*1024+1024).
// S^T = mfma_16x16x32(K-frag, Q-frag): C-layout (lane: keys quad*4+r, q=col)
// IS the B-operand layout of mfma_16x16x16 -> PV directly from registers
// (P packed via +0x8000 half-up + v_perm; no LDS round-trip, no cross-lane).
// Partial (sum e*v, sum e) of the two groups combined through LDS (valid
// because no max-subtraction is needed: |score| <= 1/8).
// ---------------------------------------------------------------------------
__global__ __launch_bounds__(512) void attn_mfma(
    const short* __restrict__ qb,  // [B,H,S,64]
    const short* __restrict__ kb,  // [B,H,S,64]
    const short* __restrict__ vt,  // [B,H,64,S]
    short* __restrict__ ob) {      // [B,H,S,64]
  // [0,32768): staging Kf[2][4096] shorts + Vf[2][4096] shorts
  // overlay after loop: Ocomb fp32[128][68] (34816 B) | lsumC[128] f32 | T 4x16x72
  __shared__ __align__(16) char smem[44544];
  short* Kf = (short*)smem;
  short* Vf = (short*)(smem + 16384);
  const int t = threadIdx.x;
  const int w = t >> 6;            // 0..7
  const int grp = w >> 2;          // key-split group
  const int wl = w & 3;            // wave within group
  const int lane = t & 63;
  const int col = lane & 15;
  const int quad = lane >> 4;
  const int bh = blockIdx.x;
  const int q0 = blockIdx.y * 128;
  const long hb = (long)bh * S_ * 64;
  const short* kg = kb + hb;
  const short* vg = vt + (long)bh * 64 * S_;

  // Q B-fragments (16x16x32): rows q0+wl*32+mt2*16+col, dims h*32+quad*8+j
  bf16x8 qa[2][2];
#pragma unroll
  for (int mt2 = 0; mt2 < 2; mt2++)
#pragma unroll
    for (int h = 0; h < 2; h++)
      qa[mt2][h] = *(const bf16x8*)&qb[hb +
          (long)(q0 + wl * 32 + mt2 * 16 + col) * 64 + h * 32 + quad * 8];

  // staging decode: each group's 256 threads stage 512 slots (2 per thread)
  const int tt = (wl << 6) | lane;   // 0..255 within group
  const int s1 = tt, s2 = tt + 256;
  // K slots: slot(nt,h,cc,qq)=nt*128+h*64+cc*4+qq holds K[nt*16+cc], chunk h*4+qq
  const int kofs1 = (((s1 >> 7) * 16 + ((s1 >> 2) & 15)) * 64) +
                    ((((s1 >> 6) & 1) * 4 + (s1 & 3)) * 8);
  const int kofs2 = (((s2 >> 7) * 16 + ((s2 >> 2) & 15)) * 64) +
                    ((((s2 >> 6) & 1) * 4 + (s2 & 3)) * 8);
  // V slots: slot'(dt,c8,cl)=dt*128+c8*16+cl holds V^T[dt*16+cl], key chunk c8
  const int vofs1 = ((s1 >> 7) * 16 + (s1 & 15)) * 2048 + ((s1 >> 4) & 7) * 8;
  const int vofs2 = ((s2 >> 7) * 16 + (s2 & 15)) * 2048 + ((s2 >> 4) & 7) * 8;

  short* KfL = Kf + grp * 4096;
  short* VfL = Vf + grp * 4096;

  f32x4 oacc[2][4] = {};
  float lsum[2] = {0.f, 0.f};

  const int kend = grp * 1024 + 1024;
  for (int kt = grp * 1024; kt < kend; kt += 64) {
    __syncthreads();
    const short* kgp = kg + (long)kt * 64;
    gload_lds16(kgp + kofs1, KfL + wl * 512);
    gload_lds16(kgp + kofs2, KfL + 2048 + wl * 512);
    gload_lds16(vg + kt + vofs1, VfL + wl * 512);
    gload_lds16(vg + kt + vofs2, VfL + 2048 + wl * 512);
    __syncthreads();

#pragma unroll
    for (int nt = 0; nt < 4; nt++) {
      const bf16x8 ka0 = *(const bf16x8*)&KfL[nt * 1024 + col * 32 + quad * 8];
      const bf16x8 ka1 = *(const bf16x8*)&KfL[nt * 1024 + 512 + col * 32 + quad * 8];
      bf16x4 pb[2];
#pragma unroll
      for (int mt2 = 0; mt2 < 2; mt2++) {
        f32x4 z = {0.f, 0.f, 0.f, 0.f};
        z = __builtin_amdgcn_mfma_f32_16x16x32_bf16(ka0, qa[mt2][0], z, 0, 0, 0);
        z = __builtin_amdgcn_mfma_f32_16x16x32_bf16(ka1, qa[mt2][1], z, 0, 0, 0);
        const float e0 = __expf(z[0] * 0.125f);
        const float e1 = __expf(z[1] * 0.125f);
        const float e2 = __expf(z[2] * 0.125f);
        const float e3 = __expf(z[3] * 0.125f);
        lsum[mt2] += (e0 + e1) + (e2 + e3);
        int pk[2] = {packbf_hu(e0, e1), packbf_hu(e2, e3)};
        pb[mt2] = *(const bf16x4*)pk;
      }
      const int c8 = nt * 2 + (quad >> 1);
      const int vb = c8 * 128 + col * 8 + (quad & 1) * 4;
#pragma unroll
      for (int dt = 0; dt < 4; dt++) {
        const bf16x4 va = *(const bf16x4*)&VfL[dt * 1024 + vb];
        oacc[0][dt] = MFMA16(va, pb[0], oacc[0][dt]);
        oacc[1][dt] = MFMA16(va, pb[1], oacc[1][dt]);
      }
    }
  }

  __syncthreads();   // staging dead; overlay becomes valid

  // reduce lsum over quads (lanes sharing col hold same-q partials)
#pragma unroll
  for (int mt2 = 0; mt2 < 2; mt2++) {
    float s = lsum[mt2];
    s += __shfl_xor(s, 16, 64);
    s += __shfl_xor(s, 32, 64);
    lsum[mt2] = s;
  }

  float* Ocomb = (float*)smem;                 // [128][68]
  float* lsumC = (float*)(smem + 34816);       // [128]
  if (grp == 1) {
#pragma unroll
    for (int mt2 = 0; mt2 < 2; mt2++) {
      const int qloc = wl * 32 + mt2 * 16 + col;
      if (quad == 0) lsumC[qloc] = lsum[mt2];
#pragma unroll
      for (int dt = 0; dt < 4; dt++)
#pragma unroll
        for (int r = 0; r < 4; r++)
          Ocomb[qloc * 68 + dt * 16 + quad * 4 + r] = oacc[mt2][dt][r];
    }
  }
  __syncthreads();
  if (grp == 0) {
    short* T = (short*)(smem + 35328) + wl * 1152;   // 16 x 72
#pragma unroll
    for (int mt2 = 0; mt2 < 2; mt2++) {
      const int qloc = wl * 32 + mt2 * 16 + col;
      const float inv = 1.0f / (lsum[mt2] + lsumC[qloc]);
#pragma unroll
      for (int dt = 0; dt < 4; dt++)
#pragma unroll
        for (int r = 0; r < 4; r++)
          T[col * 72 + dt * 16 + quad * 4 + r] =
              f2bf((oacc[mt2][dt][r] +
                    Ocomb[qloc * 68 + dt * 16 + quad * 4 + r]) * inv);
      const bf16x8 v0 = *(const bf16x8*)&T[(lane & 15) * 72 + (lane >> 4) * 16];
      const bf16x8 v1 = *(const bf16x8*)&T[(lane & 15) * 72 + (lane >> 4) * 16 + 8];
      short* orow = ob + hb +
          (long)(q0 + wl * 32 + mt2 * 16 + (lane & 15)) * 64 + (lane >> 4) * 16;
      *(bf16x8*)orow = v0;
      *(bf16x8*)(orow + 8) = v1;
    }
  }
}

// ---------------------------------------------------------------------------
// out projection: 64x128 tile (grid 512 = 2 blocks/CU), BK=32, 4 waves (2x2).
// A = O bf16 [B,H,S,64] (k -> (h,hd) remap in staging), fp32 out + bias.
// ---------------------------------------------------------------------------
__global__ __launch_bounds__(256) void out_mfma(
    const short* __restrict__ O, const short* __restrict__ W,
    const float* __restrict__ bias, float* __restrict__ out) {
  __shared__ short As[64 * 32];    // 256 x 16B chunks
  __shared__ short Bs[128 * 32];   // 512 chunks
  const int t = threadIdx.x;
  const int w = t >> 6;
  const int lane = t & 63;
  const int col = lane & 15;
  const int quad = lane >> 4;
  const int wm = w >> 1;
  const int wn = w & 1;
  const int m0 = blockIdx.y * 64;
  const int n0 = blockIdx.x * 128;

  f32x4 acc[2][4] = {};

  for (int k0 = 0; k0 < 1024; k0 += 32) {
    __syncthreads();
    {
      const int row = t >> 2;
      const int gseg = (t & 3) ^ (row & 3);
      const int n = m0 + row;
      const int bidx = n >> 11;
      const int s = n & 2047;
      const int kk = k0 + gseg * 8;
      gload_lds16(&O[((long)(bidx * 16 + (kk >> 6)) * 2048 + s) * 64 + (kk & 63)],
                  As + w * 512);
    }
#pragma unroll
    for (int i = 0; i < 2; i++) {
      const int cs = w * 2 + i;
      const int sl = cs * 64 + lane;
      const int row = sl >> 2;
      const int gseg = (sl & 3) ^ (row & 3);
      gload_lds16(&W[(n0 + row) * 1024 + k0 + gseg * 8], Bs + cs * 512);
    }
    __syncthreads();

    bf16x8 af[2], bfr[4];
#pragma unroll
    for (int mt = 0; mt < 2; mt++) {
      const int m = wm * 32 + mt * 16 + col;
      af[mt] = *(const bf16x8*)&As[m * 32 + ((quad ^ (m & 3)) * 8)];
    }
#pragma unroll
    for (int nt = 0; nt < 4; nt++) {
      const int n = wn * 64 + nt * 16 + col;
      bfr[nt] = *(const bf16x8*)&Bs[n * 32 + ((quad ^ (n & 3)) * 8)];
    }
#pragma unroll
    for (int mt = 0; mt < 2; mt++)
#pragma unroll
      for (int nt = 0; nt < 4; nt++)
        acc[mt][nt] = __builtin_amdgcn_mfma_f32_16x16x32_bf16(
            af[mt], bfr[nt], acc[mt][nt], 0, 0, 0);
  }

  float bi[4];
#pragma unroll
  for (int nt = 0; nt < 4; nt++) bi[nt] = bias[n0 + wn * 64 + nt * 16 + col];
#pragma unroll
  for (int mt = 0; mt < 2; mt++) {
#pragma unroll
    for (int r = 0; r < 4; r++) {
      const int n = m0 + wm * 32 + mt * 16 + quad * 4 + r;
#pragma unroll
      for (int nt = 0; nt < 4; nt++)
        out[(long)n * 1024 + n0 + wn * 64 + nt * 16 + col] =
            acc[mt][nt][r] + bi[nt];
    }
  }
}

// ---------------------------------------------------------------------------
extern "C" void kernel_launch(void* const* d_in, const int* in_sizes, int n_in,
                              void* d_out, int out_size, void* d_ws,
                              size_t ws_size, hipStream_t stream) {
  const float* tokens = (const float*)d_in[0];
  const float* qkv_w = (const float*)d_in[1];
  const float* qkv_b = (const float*)d_in[2];
  const float* out_w = (const float*)d_in[3];
  const float* out_b = (const float*)d_in[4];
  float* out = (float*)d_out;

  const size_t per = (size_t)BHS * HD_;          // 4,194,304 elements
  float* tab = (float*)d_ws;                     // 2048*32*2 floats = 512 KB
  short* tok_bf = (short*)(tab + 2048 * 64);
  short* qkvw_bf = tok_bf + per;                 // 3M shorts
  short* outw_bf = qkvw_bf + 3 * per / 4;        // 1M
  short* q_bf = outw_bf + per / 4;               // 4M
  short* k_bf = q_bf + per;                      // 4M
  short* vt_bf = k_bf + per;                     // 4M
  short* O_bf = vt_bf + per;                     // 4M  (~48.5 MB total)

  // 1) casts + rope table
  hipLaunchKernelGGL(prep, dim3(4128), dim3(256), 0, stream, tokens, qkv_w,
                     out_w, tok_bf, qkvw_bf, outw_bf, tab);
  // 2) QKV projection + fused RoPE/norm (q,k) + fused V transpose
  hipLaunchKernelGGL(qkv_mfma, dim3(24, 32), dim3(256), 0, stream, tok_bf,
                     qkvw_bf, qkv_b, tab, q_bf, k_bf, vt_bf);
  // 3) Attention (S^T, in-register P, in-block key split)
  hipLaunchKernelGGL(attn_mfma, dim3(B_ * H_, S_ / 128), dim3(512), 0, stream,
                     q_bf, k_bf, vt_bf, O_bf);
  // 4) Output projection
  hipLaunchKernelGGL(out_mfma, dim3(8, 64), dim3(256), 0, stream, O_bf,
                     outw_bf, out_b, out);
}